// Round 18
// baseline (449.605 us; speedup 1.0000x reference)
//
#include <hip/hip_runtime.h>
#include <hip/hip_bf16.h>

#define BATCH 16
#define NTOK 578
#define NTOKP 592
#define NP 576
#define PGRID 24
#define DIM 768
#define NH 12
#define HDIM 64
#define BAND 64
#define SDIM 16
#define HID 3072
#define SCALE 0.125f
#define CLIPV 10.0f
#define KHS 104
#define VTS 72
#define PLS 72
#define FKS 16   // film k-splits

typedef __attribute__((ext_vector_type(8))) short bf16x8;
typedef __attribute__((ext_vector_type(4))) float f32x4;

__device__ __forceinline__ float b2f(short u) {
  union { float f; unsigned int i; } x;
  x.i = ((unsigned int)(unsigned short)u) << 16;
  return x.f;
}
__device__ __forceinline__ short f2b(float x) {
  __hip_bfloat16 h = __float2bfloat16(x);
  return *reinterpret_cast<short*>(&h);
}

__device__ __forceinline__ void gload16(const short* g, short* l) {
  __builtin_amdgcn_global_load_lds(
      (const __attribute__((address_space(1))) unsigned int*)g,
      (__attribute__((address_space(3))) unsigned int*)l, 16, 0, 0);
}

// bijective XCD-chunk swizzle (m204)
__device__ __forceinline__ int swz_wgid(int orig, int nwg) {
  int xcd = orig & 7, i = orig >> 3;
  int q = nwg >> 3, r = nwg & 7;
  return (xcd < r) ? xcd * (q + 1) + i : r * (q + 1) + (xcd - r) * q + i;
}

__device__ __forceinline__ void block_reduce2(float& a, float& b) {
  __shared__ float sm[8];
  #pragma unroll
  for (int o = 32; o > 0; o >>= 1) { a += __shfl_down(a, o); b += __shfl_down(b, o); }
  int lane = threadIdx.x & 63, w = threadIdx.x >> 6;
  __syncthreads();
  if (lane == 0) { sm[w] = a; sm[4 + w] = b; }
  __syncthreads();
  a = sm[0] + sm[1] + sm[2] + sm[3];
  b = sm[4] + sm[5] + sm[6] + sm[7];
}

// -------- transpose: 256(k) x 64(n) tile --------
#define TKS 266
__device__ __forceinline__ void tw2(
    const float* __restrict__ W, short* __restrict__ Wt, int K, int N,
    int kblk, int nblk, short* t) {
  int tid = threadIdx.x;
  int k0 = kblk * 256, n0 = nblk * 64;
  int r0 = tid >> 4, c0 = (tid & 15) * 4;
  #pragma unroll
  for (int it = 0; it < 16; it++) {
    int r = it * 16 + r0;
    float4 v = *(const float4*)(W + (size_t)(k0 + r) * N + n0 + c0);
    t[(c0 + 0) * TKS + r] = f2b(v.x);
    t[(c0 + 1) * TKS + r] = f2b(v.y);
    t[(c0 + 2) * TKS + r] = f2b(v.z);
    t[(c0 + 3) * TKS + r] = f2b(v.w);
  }
  __syncthreads();
  int n1 = tid >> 5, k1 = (tid & 31) * 8;
  #pragma unroll
  for (int it = 0; it < 8; it++) {
    int n = it * 8 + n1;
    *(bf16x8*)(Wt + (size_t)(n0 + n) * K + k0 + k1) = *(bf16x8*)(t + n * TKS + k1);
  }
}

// -------- weight prep: 4 transposes + dwt reorder --------
__global__ __launch_bounds__(256) void prep_weights(
    const float* __restrict__ qkv_w, const float* __restrict__ proj_w,
    const float* __restrict__ fc1_w, const float* __restrict__ fc2_w,
    const float* __restrict__ dww,
    short* __restrict__ qkvT, short* __restrict__ projT,
    short* __restrict__ fc1T, short* __restrict__ fc2T, float* __restrict__ dwt) {
  __shared__ short t[64 * TKS];
  int id = blockIdx.x;
  if (id < 108) {
    tw2(qkv_w, qkvT, 768, 2304, id % 3, id / 3, t);
  } else if (id < 144) {
    int u = id - 108; tw2(proj_w, projT, 768, 768, u % 3, u / 3, t);
  } else if (id < 288) {
    int u = id - 144; tw2(fc1_w, fc1T, 768, 3072, u % 3, u / 3, t);
  } else if (id < 432) {
    int u = id - 288; tw2(fc2_w, fc2T, 3072, 768, u % 12, u / 12, t);
  } else {
    int i = (id - 432) * 256 + threadIdx.x;
    if (i < 9 * HID) { int tt = i / HID, c = i - tt * HID; dwt[i] = dww[c * 9 + tt]; }
  }
}

// -------- FiLM stage 1: k-split partials --------
__global__ __launch_bounds__(256) void film_part(
    const float* __restrict__ fsum, const float* __restrict__ film_w,
    float* __restrict__ part) {
  __shared__ float fs[BATCH][48];
  int bid = blockIdx.x;
  int cg = bid % 12, ks = bid / 12;
  int tid = threadIdx.x;
  int k0 = ks * 48;
  for (int i = tid; i < BATCH * 48; i += 256) {
    int b = i / 48, kk = i - b * 48;
    fs[b][kk] = fsum[b * DIM + k0 + kk];
  }
  __syncthreads();
  int col4 = cg * 128 + (tid & 31) * 4;
  int bq = tid >> 5;
  float a0[4] = {0.f, 0.f, 0.f, 0.f}, a1[4] = {0.f, 0.f, 0.f, 0.f};
  #pragma unroll 4
  for (int kk = 0; kk < 48; kk++) {
    float4 w = *(const float4*)(film_w + (size_t)(k0 + kk) * 2 * DIM + col4);
    float f0 = fs[bq][kk], f1 = fs[bq + 8][kk];
    a0[0] += f0 * w.x; a0[1] += f0 * w.y; a0[2] += f0 * w.z; a0[3] += f0 * w.w;
    a1[0] += f1 * w.x; a1[1] += f1 * w.y; a1[2] += f1 * w.z; a1[3] += f1 * w.w;
  }
  *(float4*)(part + ((size_t)ks * BATCH + bq) * 1536 + col4) =
      (float4){a0[0], a0[1], a0[2], a0[3]};
  *(float4*)(part + ((size_t)ks * BATCH + bq + 8) * 1536 + col4) =
      (float4){a1[0], a1[1], a1[2], a1[3]};
}

// -------- FiLM stage 2 + gate GEMV --------
__global__ __launch_bounds__(256) void film_fin(
    const float* __restrict__ part, const float* __restrict__ film_b,
    const float* __restrict__ ftc, const float* __restrict__ gate_w,
    const float* __restrict__ gate_b,
    float* __restrict__ gamma, float* __restrict__ beta, float* __restrict__ g) {
  int bid = blockIdx.x;
  if (bid < 96) {
    int idx = bid * 256 + threadIdx.x;
    int b = idx / 1536, col = idx - b * 1536;
    float acc = film_b[col];
    #pragma unroll
    for (int ks = 0; ks < FKS; ks++)
      acc += part[((size_t)ks * BATCH + b) * 1536 + col];
    float t = tanhf(acc) * 0.5f;
    if (col < DIM) gamma[b * DIM + col] = t;
    else beta[b * DIM + (col - DIM)] = t;
  } else {
    int widx = (bid - 96) * 4 + (threadIdx.x >> 6);
    int lane = threadIdx.x & 63;
    if (widx < BATCH * NH) {
      int b = widx / NH, h = widx - b * NH;
      float acc = 0.f;
      for (int kk = lane; kk < DIM; kk += 64) acc += ftc[b * DIM + kk] * gate_w[kk * NH + h];
      #pragma unroll
      for (int o = 32; o > 0; o >>= 1) acc += __shfl_down(acc, o);
      if (lane == 0) g[widx] = tanhf(acc + gate_b[h]) * 0.05f;
    }
  }
}

// -------- band_s --------
__global__ __launch_bounds__(256) void band_s_kernel(
    const float* __restrict__ tbf, const float* __restrict__ bw, float* __restrict__ s) {
  int row = blockIdx.x * 4 + (threadIdx.x >> 6);
  int lane = threadIdx.x & 63;
  if (row >= BATCH * NTOK) return;
  const float* t = tbf + (size_t)row * BAND;
  float val = 0.f;
  if (lane < SDIM) {
    for (int i = 0; i < BAND; i++) val += t[i] * bw[i * SDIM + lane];
  }
  float ss = val * val;
  #pragma unroll
  for (int o = 8; o > 0; o >>= 1) ss += __shfl_xor(ss, o, 16);
  if (lane < SDIM) s[(size_t)row * SDIM + lane] = val * rsqrtf(ss * (1.f / 16.f) + 1e-6f);
}

// -------- v -> vT --------
__global__ __launch_bounds__(256) void transpose_v(
    const short* __restrict__ v, short* __restrict__ vT) {
  __shared__ short t[64][72];
  int bh = blockIdx.y;
  int n0 = blockIdx.x * 64;
  int tid = threadIdx.x;
  const short* vb = v + (size_t)bh * NTOK * HDIM;
  short* ob = vT + (size_t)bh * HDIM * NTOKP;
  {
    int r = tid >> 2, c0 = (tid & 3) * 16;
    int n = n0 + r;
    bf16x8 a0 = {0,0,0,0,0,0,0,0}, a1 = {0,0,0,0,0,0,0,0};
    if (n < NTOK) {
      a0 = *(const bf16x8*)(vb + (size_t)n * HDIM + c0);
      a1 = *(const bf16x8*)(vb + (size_t)n * HDIM + c0 + 8);
    }
    *(bf16x8*)(&t[r][c0]) = a0;
    *(bf16x8*)(&t[r][c0 + 8]) = a1;
  }
  __syncthreads();
  {
    int d = tid & 63, nc = tid >> 6;
    int nbase = n0 + nc * 16;
    short tmp[16];
    #pragma unroll
    for (int e = 0; e < 16; e++) tmp[e] = t[nc * 16 + e][d];
    if (nbase + 16 <= NTOK) {
      *(bf16x8*)(ob + (size_t)d * NTOKP + nbase) = *(bf16x8*)tmp;
      *(bf16x8*)(ob + (size_t)d * NTOKP + nbase + 8) = *(bf16x8*)(tmp + 8);
    } else {
      for (int e = 0; e < 16; e++)
        if (nbase + e < NTOK) ob[(size_t)d * NTOKP + nbase + e] = tmp[e];
    }
  }
}

// -------- LN(gate)+FiLM -> xw ; LN(attn) -> xn --------
__global__ __launch_bounds__(256) void ln_film_kernel(
    const float* __restrict__ x, const float* __restrict__ gamma, const float* __restrict__ beta,
    const float* __restrict__ gw, const float* __restrict__ gb,
    const float* __restrict__ aw, const float* __restrict__ ab,
    const float* __restrict__ alpha, float* __restrict__ xw, __hip_bfloat16* __restrict__ xn) {
  int row = blockIdx.x;
  int b = row / NTOK, n = row % NTOK;
  int tid = threadIdx.x;
  const float* xr = x + (size_t)row * DIM;
  float vals[3];
  #pragma unroll
  for (int j = 0; j < 3; j++) vals[j] = xr[tid + j * 256];
  if (n >= 2) {
    float s = vals[0] + vals[1] + vals[2];
    float ss = vals[0]*vals[0] + vals[1]*vals[1] + vals[2]*vals[2];
    block_reduce2(s, ss);
    float mean = s * (1.f / 768.f);
    float inv = rsqrtf(ss * (1.f / 768.f) - mean * mean + 1e-6f);
    float a = alpha[0];
    #pragma unroll
    for (int j = 0; j < 3; j++) {
      int d = tid + j * 256;
      float p = (vals[j] - mean) * inv * gw[d] + gb[d];
      vals[j] = p * (1.f + a * gamma[(size_t)b * DIM + d]) + a * beta[(size_t)b * DIM + d];
    }
  }
  float* xwr = xw + (size_t)row * DIM;
  #pragma unroll
  for (int j = 0; j < 3; j++) xwr[tid + j * 256] = vals[j];
  float s = vals[0] + vals[1] + vals[2];
  float ss = vals[0]*vals[0] + vals[1]*vals[1] + vals[2]*vals[2];
  block_reduce2(s, ss);
  float mean = s * (1.f / 768.f);
  float inv = rsqrtf(ss * (1.f / 768.f) - mean * mean + 1e-6f);
  __hip_bfloat16* xnr = xn + (size_t)row * DIM;
  #pragma unroll
  for (int j = 0; j < 3; j++) {
    int d = tid + j * 256;
    xnr[d] = __float2bfloat16((vals[j] - mean) * inv * aw[d] + ab[d]);
  }
}

// ======== 256x128 MFMA core (single buffer, XOR-swizzled LDS) ========
__device__ __forceinline__ void stage_tile256(
    const short* __restrict__ A, const short* __restrict__ Wt, int K,
    int m0, int n0, int kt, short* Al, short* Bl, int wid, int lrow, int lcolsw) {
  #pragma unroll
  for (int it = 0; it < 4; it++) {
    int r0 = wid * 8 + it * 64;
    gload16(A + (size_t)(m0 + r0 + lrow) * K + kt + lcolsw, Al + r0 * 64);
  }
  #pragma unroll
  for (int it = 0; it < 2; it++) {
    int r0 = wid * 8 + it * 64;
    gload16(Wt + (size_t)(n0 + r0 + lrow) * K + kt + lcolsw, Bl + r0 * 64);
  }
}

__device__ __forceinline__ void compute_tile256(
    const short* Al, const short* Bl, f32x4 acc[4][4],
    int wr, int wc, int ln15, int kb) {
  int rx = ln15 & 7;
  #pragma unroll
  for (int kk = 0; kk < 2; kk++) {
    int csw = ((kk * 4 + kb) ^ rx) * 8;
    bf16x8 af[4], bfr[4];
    #pragma unroll
    for (int i = 0; i < 4; i++)
      af[i] = *(const bf16x8*)(Al + (wr * 64 + i * 16 + ln15) * 64 + csw);
    #pragma unroll
    for (int j = 0; j < 4; j++)
      bfr[j] = *(const bf16x8*)(Bl + (wc * 64 + j * 16 + ln15) * 64 + csw);
    #pragma unroll
    for (int i = 0; i < 4; i++)
      #pragma unroll
      for (int j = 0; j < 4; j++)
        acc[i][j] = __builtin_amdgcn_mfma_f32_16x16x32_bf16(af[i], bfr[j], acc[i][j], 0, 0, 0);
  }
}

__device__ __forceinline__ void mfma_core_256(
    const short* __restrict__ A, const short* __restrict__ Wt,
    int K, int m0, int n0, f32x4 acc[4][4], short* Al, short* Bl) {
  int tid = threadIdx.x, lane = tid & 63, wid = tid >> 6;
  int wr = wid >> 1, wc = wid & 1;
  int ln15 = lane & 15, kb = lane >> 4;
  int lrow = lane >> 3;
  int lcolsw = (((lane & 7) ^ lrow) & 7) * 8;
  #pragma unroll
  for (int i = 0; i < 4; i++)
    #pragma unroll
    for (int j = 0; j < 4; j++) acc[i][j] = (f32x4){0.f, 0.f, 0.f, 0.f};
  for (int kt = 0; kt < K; kt += 64) {
    stage_tile256(A, Wt, K, m0, n0, kt, Al, Bl, wid, lrow, lcolsw);
    __syncthreads();
    compute_tile256(Al, Bl, acc, wr, wc, ln15, kb);
    __syncthreads();
  }
}

// ======== 64x128 MFMA core (counted-vmcnt dbuf, XOR-swizzled) ========
__device__ __forceinline__ void stage_tile64(
    const short* __restrict__ A, const short* __restrict__ Wt, int K,
    int m0, int n0, int kt, short* Al, short* Bl, int wid, int lrow, int lcolsw) {
  #pragma unroll
  for (int it = 0; it < 2; it++) {
    int r0 = wid * 8 + it * 32;
    gload16(A + (size_t)(m0 + r0 + lrow) * K + kt + lcolsw, Al + r0 * 64);
  }
  #pragma unroll
  for (int it = 0; it < 4; it++) {
    int r0 = wid * 8 + it * 32;
    gload16(Wt + (size_t)(n0 + r0 + lrow) * K + kt + lcolsw, Bl + r0 * 64);
  }
}

__device__ __forceinline__ void compute_tile64(
    const short* Al, const short* Bl, f32x4 acc[4][2],
    int wid, int ln15, int kb) {
  int rx = ln15 & 7;
  #pragma unroll
  for (int kk = 0; kk < 2; kk++) {
    int csw = ((kk * 4 + kb) ^ rx) * 8;
    bf16x8 af[4], bfr[2];
    #pragma unroll
    for (int i = 0; i < 4; i++)
      af[i] = *(const bf16x8*)(Al + (i * 16 + ln15) * 64 + csw);
    #pragma unroll
    for (int j = 0; j < 2; j++)
      bfr[j] = *(const bf16x8*)(Bl + (wid * 32 + j * 16 + ln15) * 64 + csw);
    #pragma unroll
    for (int i = 0; i < 4; i++)
      #pragma unroll
      for (int j = 0; j < 2; j++)
        acc[i][j] = __builtin_amdgcn_mfma_f32_16x16x32_bf16(af[i], bfr[j], acc[i][j], 0, 0, 0);
  }
}

__device__ __forceinline__ void mfma_core_64(
    const short* __restrict__ A, const short* __restrict__ Wt,
    int K, int m0, int n0, f32x4 acc[4][2],
    short* Al0, short* Bl0, short* Al1, short* Bl1) {
  int tid = threadIdx.x, lane = tid & 63, wid = tid >> 6;
  int ln15 = lane & 15, kb = lane >> 4;
  int lrow = lane >> 3;
  int lcolsw = (((lane & 7) ^ lrow) & 7) * 8;
  #pragma unroll
  for (int i = 0; i < 4; i++)
    #pragma unroll
    for (int j = 0; j < 2; j++) acc[i][j] = (f32x4){0.f, 0.f, 0.f, 0.f};
  stage_tile64(A, Wt, K, m0, n0, 0, Al0, Bl0, wid, lrow, lcolsw);
  stage_tile64(A, Wt, K, m0, n0, 64, Al1, Bl1, wid, lrow, lcolsw);
  asm volatile("s_waitcnt vmcnt(6)" ::: "memory");
  __builtin_amdgcn_s_barrier();
  const int NKT = K >> 6;
  for (int t = 0; t < NKT; t++) {
    const short* Ac = (t & 1) ? Al1 : Al0;
    const short* Bc = (t & 1) ? Bl1 : Bl0;
    compute_tile64(Ac, Bc, acc, wid, ln15, kb);
    __builtin_amdgcn_s_barrier();
    if (t + 2 < NKT) {
      short* As = (t & 1) ? Al1 : Al0;
      short* Bs = (t & 1) ? Bl1 : Bl0;
      stage_tile64(A, Wt, K, m0, n0, (t + 2) << 6, As, Bs, wid, lrow, lcolsw);
      asm volatile("s_waitcnt vmcnt(6)" ::: "memory");
    } else if (t + 1 < NKT) {
      asm volatile("s_waitcnt vmcnt(0)" ::: "memory");
    }
    __builtin_amdgcn_s_barrier();
  }
}

// -------- K4: qkv GEMM (256x128, n-major) + fused RMS+SCALE --------
__global__ __launch_bounds__(512) void gemm_qkv(
    const short* __restrict__ A, const short* __restrict__ Wt, const float* __restrict__ bias,
    __hip_bfloat16* __restrict__ q, __hip_bfloat16* __restrict__ k, __hip_bfloat16* __restrict__ v) {
  __shared__ short Al[256 * 64], Bl[128 * 64];
  f32x4 acc[4][4];
  int wgid = swz_wgid(blockIdx.x, 37 * 18);
  int m0 = (wgid % 37) * 256, n0 = (wgid / 37) * 128;
  mfma_core_256(A, Wt, DIM, m0, n0, acc, Al, Bl);
  int tid = threadIdx.x, lane = tid & 63, wid = tid >> 6, wr = wid >> 1, wc = wid & 1;
  int ln15 = lane & 15, lq = lane >> 4;
  int colbase = n0 + wc * 64;
  int which = colbase / DIM;
  int rem = colbase - which * DIM;
  int h = rem >> 6;
  __hip_bfloat16* dst = (which == 0) ? q : ((which == 1) ? k : v);
  float fin_scale = (which == 0) ? SCALE : 1.0f;
  float bv[4];
  #pragma unroll
  for (int j = 0; j < 4; j++) bv[j] = bias[colbase + j * 16 + ln15];
  #pragma unroll
  for (int i = 0; i < 4; i++) {
    #pragma unroll
    for (int r = 0; r < 4; r++) {
      int m = m0 + wr * 64 + i * 16 + lq * 4 + r;
      float v4[4];
      #pragma unroll
      for (int j = 0; j < 4; j++) v4[j] = acc[i][j][r] + bv[j];
      float inv = fin_scale;
      if (which < 2) {
        float ss = v4[0]*v4[0] + v4[1]*v4[1] + v4[2]*v4[2] + v4[3]*v4[3];
        ss += __shfl_xor(ss, 1); ss += __shfl_xor(ss, 2);
        ss += __shfl_xor(ss, 4); ss += __shfl_xor(ss, 8);
        inv = rsqrtf(ss * (1.f / 64.f) + 1e-6f) * fin_scale;
      }
      if (m < BATCH * NTOK) {
        int b = m / NTOK, n = m - b * NTOK;
        __hip_bfloat16* orow = dst + (((size_t)b * NH + h) * NTOK + n) * HDIM;
        #pragma unroll
        for (int j = 0; j < 4; j++)
          orow[j * 16 + ln15] = __float2bfloat16(v4[j] * inv);
      }
    }
  }
}

// -------- K6: MFMA flash attention, 64 q-rows/block, 4 waves, 1920 blocks --------
__global__ __launch_bounds__(256) void attn_mfma(
    const short* __restrict__ q, const short* __restrict__ k,
    const short* __restrict__ vT, const float* __restrict__ s,
    const float* __restrict__ g, const float* __restrict__ alpha,
    const float* __restrict__ sbs, short* __restrict__ ao) {
  __shared__ short Kh[64 * KHS];      // 13.3 KB single
  __shared__ short Vt[2][64 * VTS];   // 18.4 KB
  __shared__ short Pl[4][16 * PLS];   // 9.2 KB   -> ~41 KB total
  int xcd = blockIdx.x & 7, idx = blockIdx.x >> 3;
  int bh = xcd * 24 + idx / 10;
  int n0 = (idx % 10) * 64;
  int b = bh / NH, h = bh - b * NH;
  int tid = threadIdx.x, lane = tid & 63, w = tid >> 6;
  int l15 = lane & 15, lg = lane >> 4;
  float a = alpha[0], c = a * sbs[0];
  const short* qb = q + (size_t)bh * NTOK * HDIM;
  const short* kb = k + (size_t)bh * NTOK * HDIM;
  const short* vtb = vT + (size_t)bh * HDIM * NTOKP;
  const float* sb = s + (size_t)b * NTOK * SDIM;
  const bf16x8 Z8 = {0, 0, 0, 0, 0, 0, 0, 0};

  int qrow = n0 + w * 16 + l15;
  int qsrc = (qrow < NTOK) ? qrow : 0;
  bf16x8 qf0 = *(const bf16x8*)(qb + (size_t)qsrc * HDIM + lg * 8);
  bf16x8 qf1 = *(const bf16x8*)(qb + (size_t)qsrc * HDIM + 32 + lg * 8);
  bf16x8 qf2 = Z8;
  if (lg < 2) {
    const float* sp = sb + (size_t)qsrc * SDIM + lg * 8;
    #pragma unroll
    for (int j = 0; j < 8; j++) qf2[j] = f2b(c * sp[j]);
  }

  f32x4 accO[4];
  #pragma unroll
  for (int dd = 0; dd < 4; dd++) accO[dd] = (f32x4){0.f, 0.f, 0.f, 0.f};
  float rsum[4] = {0.f, 0.f, 0.f, 0.f};

  int srow = tid >> 2, sseg = tid & 3;   // 256 thr: srow 0..63
  if (sseg == 3) {   // one-time zero of Khat dims 80..95
    short* dst = Kh + srow * KHS + 80;
    *(bf16x8*)dst = Z8;
    *(bf16x8*)(dst + 8) = Z8;
  }

  auto stageK = [&](int mt) {
    int key = mt + srow;
    bool kok = key < NTOK;
    if (sseg < 2) {
      bf16x8 v0 = Z8, v1 = Z8, v2 = Z8, v3 = Z8;
      if (kok) {
        const short* src = kb + (size_t)key * HDIM + sseg * 32;
        v0 = *(const bf16x8*)(src);
        v1 = *(const bf16x8*)(src + 8);
        v2 = *(const bf16x8*)(src + 16);
        v3 = *(const bf16x8*)(src + 24);
      }
      short* dst = Kh + srow * KHS + sseg * 32;
      *(bf16x8*)dst = v0;
      *(bf16x8*)(dst + 8) = v1;
      *(bf16x8*)(dst + 16) = v2;
      *(bf16x8*)(dst + 24) = v3;
    } else if (sseg == 2) {
      bf16x8 v0 = Z8, v1 = Z8;
      if (kok) {
        const float* sp = sb + (size_t)key * SDIM;
        #pragma unroll
        for (int j = 0; j < 8; j++) { v0[j] = f2b(sp[j]); v1[j] = f2b(sp[j + 8]); }
      }
      short* dst = Kh + srow * KHS + 64;
      *(bf16x8*)dst = v0;
      *(bf16x8*)(dst + 8) = v1;
    }
  };
  auto stageV = [&](int mt, short* VtB) {
    int kk0 = sseg * 16;
    short* dst = VtB + srow * VTS + kk0;
    const short* src = vtb + (size_t)srow * NTOKP + mt + kk0;
    if (mt + kk0 + 16 <= NTOK) {
      *(bf16x8*)dst = *(const bf16x8*)src;
      *(bf16x8*)(dst + 8) = *(const bf16x8*)(src + 8);
    } else {
      for (int e = 0; e < 16; e++)
        dst[e] = (mt + kk0 + e < NTOK) ? src[e] : (short)0;
    }
  };

  stageK(0);
  stageV(0, Vt[0]);
  __syncthreads();
  const int NT = 10;
  for (int ti = 0; ti < NT; ti++) {
    int mt = ti * 64, cur = ti & 1;
    const short* VtC = Vt[cur];
    // ---- QK from Kh ----
    f32x4 sa[4];
    __builtin_amdgcn_s_setprio(1);
    #pragma unroll
    for (int jj = 0; jj < 4; jj++) {
      sa[jj] = (f32x4){0.f, 0.f, 0.f, 0.f};
      const short* kp = Kh + (jj * 16 + l15) * KHS + lg * 8;
      sa[jj] = __builtin_amdgcn_mfma_f32_16x16x32_bf16(qf0, *(const bf16x8*)kp, sa[jj], 0, 0, 0);
      sa[jj] = __builtin_amdgcn_mfma_f32_16x16x32_bf16(qf1, *(const bf16x8*)(kp + 32), sa[jj], 0, 0, 0);
      sa[jj] = __builtin_amdgcn_mfma_f32_16x16x32_bf16(qf2, *(const bf16x8*)(kp + 64), sa[jj], 0, 0, 0);
    }
    __builtin_amdgcn_s_setprio(0);
    __syncthreads();   // all waves done reading Kh
    if (ti + 1 < NT) {
      stageK(mt + 64);
      stageV(mt + 64, Vt[cur ^ 1]);
    }
    // ---- softmax (overlaps staging latency) ----
    short* pw = Pl[w];
    float ps[4][4];
    #pragma unroll
    for (int jj = 0; jj < 4; jj++) {
      bool ok = (mt + jj * 16 + l15) < NTOK;
      #pragma unroll
      for (int r = 0; r < 4; r++) {
        float x = sa[jj][r];
        x = fminf(fmaxf(x, -CLIPV), CLIPV);
        float e = ok ? __expf(x) : 0.f;
        ps[jj][r] = e;
        pw[(lg * 4 + r) * PLS + jj * 16 + l15] = f2b(e);
      }
    }
    #pragma unroll
    for (int r = 0; r < 4; r++) {
      float t = ps[0][r] + ps[1][r] + ps[2][r] + ps[3][r];
      t += __shfl_xor(t, 1); t += __shfl_xor(t, 2);
      t += __shfl_xor(t, 4); t += __shfl_xor(t, 8);
      rsum[r] += t;
    }
    // ---- PV from Vt[cur] ----
    __builtin_amdgcn_s_setprio(1);
    #pragma unroll
    for (int kc = 0; kc < 2; kc++) {
      bf16x8 pa = *(const bf16x8*)(pw + l15 * PLS + kc * 32 + lg * 8);
      #pragma unroll
      for (int dd = 0; dd < 4; dd++) {
        bf16x8 vf = *(const bf16x8*)(VtC + (dd * 16 + l15) * VTS + kc * 32 + lg * 8);
        accO[dd] = __builtin_amdgcn_mfma_f32_16x16x32_bf16(pa, vf, accO[dd], 0, 0, 0);
      }
    }
    __builtin_amdgcn_s_setprio(0);
    __syncthreads();   // staging complete
  }
  float gm = 1.f + a * g[bh];
  #pragma unroll
  for (int r = 0; r < 4; r++) {
    int n = n0 + w * 16 + lg * 4 + r;
    if (n >= NTOK) continue;
    float inv = gm / rsum[r];
    short* orow = ao + ((size_t)b * NTOK + n) * DIM + h * HDIM;
    #pragma unroll
    for (int dd = 0; dd < 4; dd++)
      orow[dd * 16 + l15] = f2b(accO[dd][r] * inv);
  }
}

// -------- K7: proj GEMM (64x128 counted, n-major) + residual --------
__global__ __launch_bounds__(256) void gemm_proj(
    const short* __restrict__ A, const short* __restrict__ Wt, const float* __restrict__ bias,
    float* __restrict__ xw, float* __restrict__ out) {
  __shared__ short Al0[64 * 64], Bl0[128 * 64], Al1[64 * 64], Bl1[128 * 64];
  f32x4 acc[4][2];
  int wgid = swz_wgid(blockIdx.x, 145 * 6);
  int m0 = (wgid % 145) * 64, n0 = (wgid / 145) * 128;
  mfma_core_64(A, Wt, DIM, m0, n0, acc, Al0, Bl0, Al1, Bl1);
  int tid = threadIdx.x, lane = tid & 63, wid = tid >> 6;
  int ln15 = lane & 15, lq = lane >> 4;
  #pragma unroll
  for (int i = 0; i < 4; i++) {
    #pragma unroll
    for (int j = 0; j < 2; j++) {
      int col = n0 + wid * 32 + j * 16 + ln15;
      float bv = bias[col];
      #pragma unroll
      for (int r = 0; r < 4; r++) {
        int m = m0 + i * 16 + lq * 4 + r;
        if (m >= BATCH * NTOK) continue;
        int n = m % NTOK;
        float val = acc[i][j][r] + bv + xw[(size_t)m * DIM + col];
        xw[(size_t)m * DIM + col] = val;
        if (n < 2) out[(size_t)m * DIM + col] = val;
      }
    }
  }
}

// -------- K8: LN for MLP -> xm bf16 --------
__global__ __launch_bounds__(256) void ln_mlp_kernel(
    const float* __restrict__ x2, const float* __restrict__ w, const float* __restrict__ bb,
    __hip_bfloat16* __restrict__ xm) {
  int r = blockIdx.x;
  int b = r / NP, pi = r % NP;
  int tid = threadIdx.x;
  const float* xr = x2 + ((size_t)b * NTOK + 2 + pi) * DIM;
  float vals[3];
  #pragma unroll
  for (int j = 0; j < 3; j++) vals[j] = xr[tid + j * 256];
  float s = vals[0] + vals[1] + vals[2];
  float ss = vals[0]*vals[0] + vals[1]*vals[1] + vals[2]*vals[2];
  block_reduce2(s, ss);
  float mean = s * (1.f / 768.f);
  float inv = rsqrtf(ss * (1.f / 768.f) - mean * mean + 1e-6f);
  __hip_bfloat16* xo = xm + (size_t)r * DIM;
  #pragma unroll
  for (int j = 0; j < 3; j++) {
    int d = tid + j * 256;
    xo[d] = __float2bfloat16((vals[j] - mean) * inv * w[d] + bb[d]);
  }
}

// -------- K9: fc1 GEMM (256x128 n-major, chunk) + GELU --------
__global__ __launch_bounds__(512) void gemm_fc1(
    const short* __restrict__ A, const short* __restrict__ Wt, const float* __restrict__ bias,
    __hip_bfloat16* __restrict__ h1) {
  __shared__ short Al[256 * 64], Bl[128 * 64];
  f32x4 acc[4][4];
  int wgid = swz_wgid(blockIdx.x, 18 * 24);
  int m0 = (wgid % 18) * 256, n0 = (wgid / 18) * 128;
  mfma_core_256(A, Wt, DIM, m0, n0, acc, Al, Bl);
  int tid = threadIdx.x, lane = tid & 63, wid = tid >> 6, wr = wid >> 1, wc = wid & 1;
  int ln15 = lane & 15, lq = lane >> 4;
  #pragma unroll
  for (int i = 0; i < 4; i++) {
    #pragma unroll
    for (int j = 0; j < 4; j++) {
      int col = n0 + wc * 64 + j * 16 + ln15;
      float bv = bias[col];
      #pragma unroll
      for (int r = 0; r < 4; r++) {
        int m = m0 + wr * 64 + i * 16 + lq * 4 + r;
        float val = acc[i][j][r] + bv;
        float ge = 0.5f * val * (1.f + erff(val * 0.70710678118f));
        h1[(size_t)m * HID + col] = __float2bfloat16(ge);
      }
    }
  }
}

// -------- K10: depthwise 3x3 conv + SiLU --------
__global__ __launch_bounds__(256) void dwconv_kernel(
    const __hip_bfloat16* __restrict__ h1, const float* __restrict__ dwt,
    const float* __restrict__ dwb, __hip_bfloat16* __restrict__ h2) {
  int gx = blockIdx.x;
  int b = gx / 144, g = gx - b * 144;
  int y = g / 6, x0 = (g - y * 6) * 4;
  int tid = threadIdx.x;
  int c0 = blockIdx.y * 512 + (tid & 63) * 8;
  int x = x0 + (tid >> 6);
  const short* in = (const short*)h1 + (size_t)b * NP * HID + c0;
  bf16x8 iv[3][3];
  #pragma unroll
  for (int ky = 0; ky < 3; ky++) {
    int yy = y + ky - 1;
    #pragma unroll
    for (int kx = 0; kx < 3; kx++) {
      int xx = x + kx - 1;
      bool ok = (yy >= 0 && yy < PGRID && xx >= 0 && xx < PGRID);
      iv[ky][kx] = ok ? *(const bf16x8*)(in + (size_t)(yy * PGRID + xx) * HID)
                      : (bf16x8){0, 0, 0, 0, 0, 0, 0, 0};
    }
  }
  float acc[8];
  {
    float4 b0 = *(const float4*)(dwb + c0);
    float4 b1 = *(const float4*)(dwb + c0 + 4);
    acc[0] = b0.x; acc[1] = b0.y; acc[2] = b0.z; acc[3] = b0.w;
    acc[4] = b1.x; acc[5] = b1.y; acc[6] = b1.z; acc[7] = b1.w;
  }
  #pragma unroll
  for (int t = 0; t < 9; t++) {
    float4 w0 = *(const float4*)(dwt + t * HID + c0);
    float4 w1 = *(const float4*)(dwt + t * HID + c0 + 4);
    bf16x8 xv = iv[t / 3][t % 3];
    acc[0] += b2f(xv[0]) * w0.x; acc[1] += b2f(xv[1]) * w0.y;
    acc[2] += b2f(xv[2]) * w0.z; acc[3] += b2f(xv[3]) * w0.w;
    acc[4] += b2f(xv[4]) * w1.x; acc[5] += b2f(xv[5]) * w1.y;
    acc[6] += b2f(xv[6]) * w1.z; acc[7] += b2f(xv[7]) * w1.w;
  }
  short ov[8];
  #pragma unroll
  for (int e = 0; e < 8; e++) {
    float v = acc[e];
    ov[e] = f2b(v / (1.f + __expf(-v)));
  }
  *(bf16x8*)((short*)h2 + ((size_t)b * NP + y * PGRID + x) * HID + c0) = *(bf16x8*)ov;
}

// -------- K11: fc2 GEMM (64x128 counted, n-major, chunk) + residual --------
__global__ __launch_bounds__(256) void gemm_fc2(
    const short* __restrict__ A, const short* __restrict__ Wt, const float* __restrict__ bias,
    const float* __restrict__ xw, float* __restrict__ out, int b0) {
  __shared__ short Al0[64 * 64], Bl0[128 * 64], Al1[64 * 64], Bl1[128 * 64];
  f32x4 acc[4][2];
  int wgid = swz_wgid(blockIdx.x, 72 * 6);
  int m0 = (wgid % 72) * 64, n0 = (wgid / 72) * 128;
  mfma_core_64(A, Wt, HID, m0, n0, acc, Al0, Bl0, Al1, Bl1);
  int tid = threadIdx.x, lane = tid & 63, wid = tid >> 6;
  int ln15 = lane & 15, lq = lane >> 4;
  #pragma unroll
  for (int i = 0; i < 4; i++) {
    #pragma unroll
    for (int j = 0; j < 2; j++) {
      int col = n0 + wid * 32 + j * 16 + ln15;
      float bv = bias[col];
      #pragma unroll
      for (int r = 0; r < 4; r++) {
        int m = m0 + i * 16 + lq * 4 + r;
        int bl = m / NP, pi = m - bl * NP;
        size_t orow = ((size_t)(b0 + bl) * NTOK + 2 + pi) * DIM;
        out[orow + col] = acc[i][j][r] + bv + xw[orow + col];
      }
    }
  }
}

extern "C" void kernel_launch(void* const* d_in, const int* in_sizes, int n_in,
                              void* d_out, int out_size, void* d_ws, size_t ws_size,
                              hipStream_t stream) {
  const float* x      = (const float*)d_in[0];
  const float* ftc    = (const float*)d_in[2];
  const float* fsum   = (const float*)d_in[3];
  const float* tbf    = (const float*)d_in[4];
  const float* alpha  = (const float*)d_in[5];
  const float* lgw    = (const float*)d_in[6];
  const float* lgb    = (const float*)d_in[7];
  const float* film_w = (const float*)d_in[8];
  const float* film_b = (const float*)d_in[9];
  const float* law    = (const float*)d_in[10];
  const float* lab    = (const float*)d_in[11];
  const float* qkv_w  = (const float*)d_in[12];
  const float* qkv_b  = (const float*)d_in[13];
  const float* proj_w = (const float*)d_in[14];
  const float* proj_b = (const float*)d_in[15];
  const float* sbs    = (const float*)d_in[16];
  const float* gate_w = (const float*)d_in[17];
  const float* gate_b = (const float*)d_in[18];
  const float* band_w = (const float*)d_in[19];
  const float* lmw    = (const float*)d_in[20];
  const float* lmb    = (const float*)d_in[21];
  const float* fc1_w  = (const float*)d_in[22];
  const float* fc1_b  = (const float*)d_in[23];
  const float* fc2_w  = (const float*)d_in[24];
  const float* fc2_b  = (const float*)d_in[25];
  const float* dw_w   = (const float*)d_in[26];
  const float* dw_b   = (const float*)d_in[27];
  float* out = (float*)d_out;

  float* ws = (float*)d_ws;
  const size_t SZ = (size_t)BATCH * NTOK * DIM;  // 7,102,464

  float* p_xw = ws;
  short* p_xn = (short*)(ws + SZ);
  short* p_q  = (short*)(ws + SZ + SZ / 2);
  short* p_k  = (short*)(ws + 2 * SZ);
  short* p_v  = (short*)(ws + 2 * SZ + SZ / 2);
  float* p_s  = ws + 3 * SZ;
  float* p_gamma = p_s + (size_t)BATCH * NTOK * SDIM;
  float* p_beta  = p_gamma + BATCH * DIM;
  float* p_g     = p_beta + BATCH * DIM;
  float* p_dwt   = p_g + 256;
  float* p_part  = p_dwt + 9 * HID;
  float* wtb = p_part + (size_t)FKS * BATCH * 1536;
  short* qkvT = (short*)wtb;
  short* projT = qkvT + (size_t)768 * 2304;
  short* fc1T  = projT + (size_t)768 * 768;
  short* fc2T  = fc1T + (size_t)768 * 3072;
  short* h2c   = fc2T + (size_t)3072 * 768;

  const size_t total_floats =
      3 * SZ + (size_t)BATCH * NTOK * SDIM + 2 * (size_t)BATCH * DIM + 256 + 9 * HID +
      (size_t)FKS * BATCH * 1536 +
      ((size_t)768 * 2304 + 768 * 768 + 768 * 3072 + 3072 * 768) / 2 +
      ((size_t)8 * NP * HID) / 2;
  if (ws_size < total_floats * sizeof(float)) return;

  short* p_ao = p_xn;
  short* p_xm = p_q;
  short* h1c  = p_k;
  short* p_vT = h2c;

  dim3 blk(256);

  prep_weights<<<dim3(432 + 108), blk, 0, stream>>>(
      qkv_w, proj_w, fc1_w, fc2_w, dw_w, qkvT, projT, fc1T, fc2T, p_dwt);

  film_part<<<dim3(12 * FKS), blk, 0, stream>>>(fsum, film_w, p_part);

  film_fin<<<dim3(96 + 48), blk, 0, stream>>>(
      p_part, film_b, ftc, gate_w, gate_b, p_gamma, p_beta, p_g);

  band_s_kernel<<<dim3((BATCH * NTOK + 3) / 4), blk, 0, stream>>>(tbf, band_w, p_s);

  ln_film_kernel<<<dim3(BATCH * NTOK), blk, 0, stream>>>(
      x, p_gamma, p_beta, lgw, lgb, law, lab, alpha, p_xw, (__hip_bfloat16*)p_xn);

  gemm_qkv<<<dim3(37 * 18), dim3(512), 0, stream>>>(
      p_xn, qkvT, qkv_b, (__hip_bfloat16*)p_q, (__hip_bfloat16*)p_k, (__hip_bfloat16*)p_v);

  transpose_v<<<dim3(10, BATCH * NH), blk, 0, stream>>>(p_v, p_vT);

  attn_mfma<<<dim3(1920), blk, 0, stream>>>(
      p_q, p_k, p_vT, p_s, p_g, alpha, sbs, p_ao);

  gemm_proj<<<dim3(145 * 6), blk, 0, stream>>>(p_ao, projT, proj_b, p_xw, out);

  ln_mlp_kernel<<<dim3(BATCH * NP), blk, 0, stream>>>(p_xw, lmw, lmb, (__hip_bfloat16*)p_xm);

  for (int cc = 0; cc < 2; cc++) {
    const short* Ach = p_xm + (size_t)cc * 4608 * DIM;
    gemm_fc1<<<dim3(18 * 24), dim3(512), 0, stream>>>(Ach, fc1T, fc1_b, (__hip_bfloat16*)h1c);
    dwconv_kernel<<<dim3(8 * 144, 6), blk, 0, stream>>>(
        (const __hip_bfloat16*)h1c, p_dwt, dw_b, (__hip_bfloat16*)h2c);
    gemm_fc2<<<dim3(72 * 6), blk, 0, stream>>>(h2c, fc2T, fc2_b, p_xw, out, cc * 8);
  }
}

// Round 19
// 438.529 us; speedup vs baseline: 1.0253x; 1.0253x over previous
//
#include <hip/hip_runtime.h>
#include <hip/hip_bf16.h>

#define BATCH 16
#define NTOK 578
#define NTOKP 592
#define NP 576
#define PGRID 24
#define DIM 768
#define NH 12
#define HDIM 64
#define BAND 64
#define SDIM 16
#define HID 3072
#define SCALE 0.125f
#define CLIPV 10.0f
#define KHS 104
#define VTS 72
#define PLS 72
#define FKS 16   // film k-splits

typedef __attribute__((ext_vector_type(8))) short bf16x8;
typedef __attribute__((ext_vector_type(4))) float f32x4;

__device__ __forceinline__ float b2f(short u) {
  union { float f; unsigned int i; } x;
  x.i = ((unsigned int)(unsigned short)u) << 16;
  return x.f;
}
__device__ __forceinline__ short f2b(float x) {
  __hip_bfloat16 h = __float2bfloat16(x);
  return *reinterpret_cast<short*>(&h);
}

__device__ __forceinline__ void gload16(const short* g, short* l) {
  __builtin_amdgcn_global_load_lds(
      (const __attribute__((address_space(1))) unsigned int*)g,
      (__attribute__((address_space(3))) unsigned int*)l, 16, 0, 0);
}

// bijective XCD-chunk swizzle (m204)
__device__ __forceinline__ int swz_wgid(int orig, int nwg) {
  int xcd = orig & 7, i = orig >> 3;
  int q = nwg >> 3, r = nwg & 7;
  return (xcd < r) ? xcd * (q + 1) + i : r * (q + 1) + (xcd - r) * q + i;
}

__device__ __forceinline__ void block_reduce2(float& a, float& b) {
  __shared__ float sm[8];
  #pragma unroll
  for (int o = 32; o > 0; o >>= 1) { a += __shfl_down(a, o); b += __shfl_down(b, o); }
  int lane = threadIdx.x & 63, w = threadIdx.x >> 6;
  __syncthreads();
  if (lane == 0) { sm[w] = a; sm[4 + w] = b; }
  __syncthreads();
  a = sm[0] + sm[1] + sm[2] + sm[3];
  b = sm[4] + sm[5] + sm[6] + sm[7];
}

// -------- transpose: 256(k) x 64(n) tile --------
#define TKS 266
__device__ __forceinline__ void tw2(
    const float* __restrict__ W, short* __restrict__ Wt, int K, int N,
    int kblk, int nblk, short* t) {
  int tid = threadIdx.x;
  int k0 = kblk * 256, n0 = nblk * 64;
  int r0 = tid >> 4, c0 = (tid & 15) * 4;
  #pragma unroll
  for (int it = 0; it < 16; it++) {
    int r = it * 16 + r0;
    float4 v = *(const float4*)(W + (size_t)(k0 + r) * N + n0 + c0);
    t[(c0 + 0) * TKS + r] = f2b(v.x);
    t[(c0 + 1) * TKS + r] = f2b(v.y);
    t[(c0 + 2) * TKS + r] = f2b(v.z);
    t[(c0 + 3) * TKS + r] = f2b(v.w);
  }
  __syncthreads();
  int n1 = tid >> 5, k1 = (tid & 31) * 8;
  #pragma unroll
  for (int it = 0; it < 8; it++) {
    int n = it * 8 + n1;
    *(bf16x8*)(Wt + (size_t)(n0 + n) * K + k0 + k1) = *(bf16x8*)(t + n * TKS + k1);
  }
}

// -------- weight prep: 4 transposes + dwt reorder --------
__global__ __launch_bounds__(256) void prep_weights(
    const float* __restrict__ qkv_w, const float* __restrict__ proj_w,
    const float* __restrict__ fc1_w, const float* __restrict__ fc2_w,
    const float* __restrict__ dww,
    short* __restrict__ qkvT, short* __restrict__ projT,
    short* __restrict__ fc1T, short* __restrict__ fc2T, float* __restrict__ dwt) {
  __shared__ short t[64 * TKS];
  int id = blockIdx.x;
  if (id < 108) {
    tw2(qkv_w, qkvT, 768, 2304, id % 3, id / 3, t);
  } else if (id < 144) {
    int u = id - 108; tw2(proj_w, projT, 768, 768, u % 3, u / 3, t);
  } else if (id < 288) {
    int u = id - 144; tw2(fc1_w, fc1T, 768, 3072, u % 3, u / 3, t);
  } else if (id < 432) {
    int u = id - 288; tw2(fc2_w, fc2T, 3072, 768, u % 12, u / 12, t);
  } else {
    int i = (id - 432) * 256 + threadIdx.x;
    if (i < 9 * HID) { int tt = i / HID, c = i - tt * HID; dwt[i] = dww[c * 9 + tt]; }
  }
}

// -------- FiLM stage 1: k-split partials --------
__global__ __launch_bounds__(256) void film_part(
    const float* __restrict__ fsum, const float* __restrict__ film_w,
    float* __restrict__ part) {
  __shared__ float fs[BATCH][48];
  int bid = blockIdx.x;
  int cg = bid % 12, ks = bid / 12;
  int tid = threadIdx.x;
  int k0 = ks * 48;
  for (int i = tid; i < BATCH * 48; i += 256) {
    int b = i / 48, kk = i - b * 48;
    fs[b][kk] = fsum[b * DIM + k0 + kk];
  }
  __syncthreads();
  int col4 = cg * 128 + (tid & 31) * 4;
  int bq = tid >> 5;
  float a0[4] = {0.f, 0.f, 0.f, 0.f}, a1[4] = {0.f, 0.f, 0.f, 0.f};
  #pragma unroll 4
  for (int kk = 0; kk < 48; kk++) {
    float4 w = *(const float4*)(film_w + (size_t)(k0 + kk) * 2 * DIM + col4);
    float f0 = fs[bq][kk], f1 = fs[bq + 8][kk];
    a0[0] += f0 * w.x; a0[1] += f0 * w.y; a0[2] += f0 * w.z; a0[3] += f0 * w.w;
    a1[0] += f1 * w.x; a1[1] += f1 * w.y; a1[2] += f1 * w.z; a1[3] += f1 * w.w;
  }
  *(float4*)(part + ((size_t)ks * BATCH + bq) * 1536 + col4) =
      (float4){a0[0], a0[1], a0[2], a0[3]};
  *(float4*)(part + ((size_t)ks * BATCH + bq + 8) * 1536 + col4) =
      (float4){a1[0], a1[1], a1[2], a1[3]};
}

// -------- FiLM stage 2 + gate GEMV --------
__global__ __launch_bounds__(256) void film_fin(
    const float* __restrict__ part, const float* __restrict__ film_b,
    const float* __restrict__ ftc, const float* __restrict__ gate_w,
    const float* __restrict__ gate_b,
    float* __restrict__ gamma, float* __restrict__ beta, float* __restrict__ g) {
  int bid = blockIdx.x;
  if (bid < 96) {
    int idx = bid * 256 + threadIdx.x;
    int b = idx / 1536, col = idx - b * 1536;
    float acc = film_b[col];
    #pragma unroll
    for (int ks = 0; ks < FKS; ks++)
      acc += part[((size_t)ks * BATCH + b) * 1536 + col];
    float t = tanhf(acc) * 0.5f;
    if (col < DIM) gamma[b * DIM + col] = t;
    else beta[b * DIM + (col - DIM)] = t;
  } else {
    int widx = (bid - 96) * 4 + (threadIdx.x >> 6);
    int lane = threadIdx.x & 63;
    if (widx < BATCH * NH) {
      int b = widx / NH, h = widx - b * NH;
      float acc = 0.f;
      for (int kk = lane; kk < DIM; kk += 64) acc += ftc[b * DIM + kk] * gate_w[kk * NH + h];
      #pragma unroll
      for (int o = 32; o > 0; o >>= 1) acc += __shfl_down(acc, o);
      if (lane == 0) g[widx] = tanhf(acc + gate_b[h]) * 0.05f;
    }
  }
}

// -------- band_s --------
__global__ __launch_bounds__(256) void band_s_kernel(
    const float* __restrict__ tbf, const float* __restrict__ bw, float* __restrict__ s) {
  int row = blockIdx.x * 4 + (threadIdx.x >> 6);
  int lane = threadIdx.x & 63;
  if (row >= BATCH * NTOK) return;
  const float* t = tbf + (size_t)row * BAND;
  float val = 0.f;
  if (lane < SDIM) {
    for (int i = 0; i < BAND; i++) val += t[i] * bw[i * SDIM + lane];
  }
  float ss = val * val;
  #pragma unroll
  for (int o = 8; o > 0; o >>= 1) ss += __shfl_xor(ss, o, 16);
  if (lane < SDIM) s[(size_t)row * SDIM + lane] = val * rsqrtf(ss * (1.f / 16.f) + 1e-6f);
}

// -------- v -> vT --------
__global__ __launch_bounds__(256) void transpose_v(
    const short* __restrict__ v, short* __restrict__ vT) {
  __shared__ short t[64][72];
  int bh = blockIdx.y;
  int n0 = blockIdx.x * 64;
  int tid = threadIdx.x;
  const short* vb = v + (size_t)bh * NTOK * HDIM;
  short* ob = vT + (size_t)bh * HDIM * NTOKP;
  {
    int r = tid >> 2, c0 = (tid & 3) * 16;
    int n = n0 + r;
    bf16x8 a0 = {0,0,0,0,0,0,0,0}, a1 = {0,0,0,0,0,0,0,0};
    if (n < NTOK) {
      a0 = *(const bf16x8*)(vb + (size_t)n * HDIM + c0);
      a1 = *(const bf16x8*)(vb + (size_t)n * HDIM + c0 + 8);
    }
    *(bf16x8*)(&t[r][c0]) = a0;
    *(bf16x8*)(&t[r][c0 + 8]) = a1;
  }
  __syncthreads();
  {
    int d = tid & 63, nc = tid >> 6;
    int nbase = n0 + nc * 16;
    short tmp[16];
    #pragma unroll
    for (int e = 0; e < 16; e++) tmp[e] = t[nc * 16 + e][d];
    if (nbase + 16 <= NTOK) {
      *(bf16x8*)(ob + (size_t)d * NTOKP + nbase) = *(bf16x8*)tmp;
      *(bf16x8*)(ob + (size_t)d * NTOKP + nbase + 8) = *(bf16x8*)(tmp + 8);
    } else {
      for (int e = 0; e < 16; e++)
        if (nbase + e < NTOK) ob[(size_t)d * NTOKP + nbase + e] = tmp[e];
    }
  }
}

// -------- LN(gate)+FiLM -> xw ; LN(attn) -> xn --------
__global__ __launch_bounds__(256) void ln_film_kernel(
    const float* __restrict__ x, const float* __restrict__ gamma, const float* __restrict__ beta,
    const float* __restrict__ gw, const float* __restrict__ gb,
    const float* __restrict__ aw, const float* __restrict__ ab,
    const float* __restrict__ alpha, float* __restrict__ xw, __hip_bfloat16* __restrict__ xn) {
  int row = blockIdx.x;
  int b = row / NTOK, n = row % NTOK;
  int tid = threadIdx.x;
  const float* xr = x + (size_t)row * DIM;
  float vals[3];
  #pragma unroll
  for (int j = 0; j < 3; j++) vals[j] = xr[tid + j * 256];
  if (n >= 2) {
    float s = vals[0] + vals[1] + vals[2];
    float ss = vals[0]*vals[0] + vals[1]*vals[1] + vals[2]*vals[2];
    block_reduce2(s, ss);
    float mean = s * (1.f / 768.f);
    float inv = rsqrtf(ss * (1.f / 768.f) - mean * mean + 1e-6f);
    float a = alpha[0];
    #pragma unroll
    for (int j = 0; j < 3; j++) {
      int d = tid + j * 256;
      float p = (vals[j] - mean) * inv * gw[d] + gb[d];
      vals[j] = p * (1.f + a * gamma[(size_t)b * DIM + d]) + a * beta[(size_t)b * DIM + d];
    }
  }
  float* xwr = xw + (size_t)row * DIM;
  #pragma unroll
  for (int j = 0; j < 3; j++) xwr[tid + j * 256] = vals[j];
  float s = vals[0] + vals[1] + vals[2];
  float ss = vals[0]*vals[0] + vals[1]*vals[1] + vals[2]*vals[2];
  block_reduce2(s, ss);
  float mean = s * (1.f / 768.f);
  float inv = rsqrtf(ss * (1.f / 768.f) - mean * mean + 1e-6f);
  __hip_bfloat16* xnr = xn + (size_t)row * DIM;
  #pragma unroll
  for (int j = 0; j < 3; j++) {
    int d = tid + j * 256;
    xnr[d] = __float2bfloat16((vals[j] - mean) * inv * aw[d] + ab[d]);
  }
}

// ======== 256x128 MFMA core (single buffer, XOR-swizzled LDS) ========
__device__ __forceinline__ void stage_tile256(
    const short* __restrict__ A, const short* __restrict__ Wt, int K,
    int m0, int n0, int kt, short* Al, short* Bl, int wid, int lrow, int lcolsw) {
  #pragma unroll
  for (int it = 0; it < 4; it++) {
    int r0 = wid * 8 + it * 64;
    gload16(A + (size_t)(m0 + r0 + lrow) * K + kt + lcolsw, Al + r0 * 64);
  }
  #pragma unroll
  for (int it = 0; it < 2; it++) {
    int r0 = wid * 8 + it * 64;
    gload16(Wt + (size_t)(n0 + r0 + lrow) * K + kt + lcolsw, Bl + r0 * 64);
  }
}

__device__ __forceinline__ void compute_tile256(
    const short* Al, const short* Bl, f32x4 acc[4][4],
    int wr, int wc, int ln15, int kb) {
  int rx = ln15 & 7;
  #pragma unroll
  for (int kk = 0; kk < 2; kk++) {
    int csw = ((kk * 4 + kb) ^ rx) * 8;
    bf16x8 af[4], bfr[4];
    #pragma unroll
    for (int i = 0; i < 4; i++)
      af[i] = *(const bf16x8*)(Al + (wr * 64 + i * 16 + ln15) * 64 + csw);
    #pragma unroll
    for (int j = 0; j < 4; j++)
      bfr[j] = *(const bf16x8*)(Bl + (wc * 64 + j * 16 + ln15) * 64 + csw);
    #pragma unroll
    for (int i = 0; i < 4; i++)
      #pragma unroll
      for (int j = 0; j < 4; j++)
        acc[i][j] = __builtin_amdgcn_mfma_f32_16x16x32_bf16(af[i], bfr[j], acc[i][j], 0, 0, 0);
  }
}

__device__ __forceinline__ void mfma_core_256(
    const short* __restrict__ A, const short* __restrict__ Wt,
    int K, int m0, int n0, f32x4 acc[4][4], short* Al, short* Bl) {
  int tid = threadIdx.x, lane = tid & 63, wid = tid >> 6;
  int wr = wid >> 1, wc = wid & 1;
  int ln15 = lane & 15, kb = lane >> 4;
  int lrow = lane >> 3;
  int lcolsw = (((lane & 7) ^ lrow) & 7) * 8;
  #pragma unroll
  for (int i = 0; i < 4; i++)
    #pragma unroll
    for (int j = 0; j < 4; j++) acc[i][j] = (f32x4){0.f, 0.f, 0.f, 0.f};
  for (int kt = 0; kt < K; kt += 64) {
    stage_tile256(A, Wt, K, m0, n0, kt, Al, Bl, wid, lrow, lcolsw);
    __syncthreads();
    compute_tile256(Al, Bl, acc, wr, wc, ln15, kb);
    __syncthreads();
  }
}

// ======== 64x128 MFMA core (counted-vmcnt dbuf, XOR-swizzled) ========
__device__ __forceinline__ void stage_tile64(
    const short* __restrict__ A, const short* __restrict__ Wt, int K,
    int m0, int n0, int kt, short* Al, short* Bl, int wid, int lrow, int lcolsw) {
  #pragma unroll
  for (int it = 0; it < 2; it++) {
    int r0 = wid * 8 + it * 32;
    gload16(A + (size_t)(m0 + r0 + lrow) * K + kt + lcolsw, Al + r0 * 64);
  }
  #pragma unroll
  for (int it = 0; it < 4; it++) {
    int r0 = wid * 8 + it * 32;
    gload16(Wt + (size_t)(n0 + r0 + lrow) * K + kt + lcolsw, Bl + r0 * 64);
  }
}

__device__ __forceinline__ void compute_tile64(
    const short* Al, const short* Bl, f32x4 acc[4][2],
    int wid, int ln15, int kb) {
  int rx = ln15 & 7;
  #pragma unroll
  for (int kk = 0; kk < 2; kk++) {
    int csw = ((kk * 4 + kb) ^ rx) * 8;
    bf16x8 af[4], bfr[2];
    #pragma unroll
    for (int i = 0; i < 4; i++)
      af[i] = *(const bf16x8*)(Al + (i * 16 + ln15) * 64 + csw);
    #pragma unroll
    for (int j = 0; j < 2; j++)
      bfr[j] = *(const bf16x8*)(Bl + (wid * 32 + j * 16 + ln15) * 64 + csw);
    #pragma unroll
    for (int i = 0; i < 4; i++)
      #pragma unroll
      for (int j = 0; j < 2; j++)
        acc[i][j] = __builtin_amdgcn_mfma_f32_16x16x32_bf16(af[i], bfr[j], acc[i][j], 0, 0, 0);
  }
}

__device__ __forceinline__ void mfma_core_64(
    const short* __restrict__ A, const short* __restrict__ Wt,
    int K, int m0, int n0, f32x4 acc[4][2],
    short* Al0, short* Bl0, short* Al1, short* Bl1) {
  int tid = threadIdx.x, lane = tid & 63, wid = tid >> 6;
  int ln15 = lane & 15, kb = lane >> 4;
  int lrow = lane >> 3;
  int lcolsw = (((lane & 7) ^ lrow) & 7) * 8;
  #pragma unroll
  for (int i = 0; i < 4; i++)
    #pragma unroll
    for (int j = 0; j < 2; j++) acc[i][j] = (f32x4){0.f, 0.f, 0.f, 0.f};
  stage_tile64(A, Wt, K, m0, n0, 0, Al0, Bl0, wid, lrow, lcolsw);
  stage_tile64(A, Wt, K, m0, n0, 64, Al1, Bl1, wid, lrow, lcolsw);
  asm volatile("s_waitcnt vmcnt(6)" ::: "memory");
  __builtin_amdgcn_s_barrier();
  const int NKT = K >> 6;
  for (int t = 0; t < NKT; t++) {
    const short* Ac = (t & 1) ? Al1 : Al0;
    const short* Bc = (t & 1) ? Bl1 : Bl0;
    compute_tile64(Ac, Bc, acc, wid, ln15, kb);
    __builtin_amdgcn_s_barrier();
    if (t + 2 < NKT) {
      short* As = (t & 1) ? Al1 : Al0;
      short* Bs = (t & 1) ? Bl1 : Bl0;
      stage_tile64(A, Wt, K, m0, n0, (t + 2) << 6, As, Bs, wid, lrow, lcolsw);
      asm volatile("s_waitcnt vmcnt(6)" ::: "memory");
    } else if (t + 1 < NKT) {
      asm volatile("s_waitcnt vmcnt(0)" ::: "memory");
    }
    __builtin_amdgcn_s_barrier();
  }
}

// -------- K4: qkv GEMM (256x128, n-major) + fused RMS+SCALE --------
__global__ __launch_bounds__(512) void gemm_qkv(
    const short* __restrict__ A, const short* __restrict__ Wt, const float* __restrict__ bias,
    __hip_bfloat16* __restrict__ q, __hip_bfloat16* __restrict__ k, __hip_bfloat16* __restrict__ v) {
  __shared__ short Al[256 * 64], Bl[128 * 64];
  f32x4 acc[4][4];
  int wgid = swz_wgid(blockIdx.x, 37 * 18);
  int m0 = (wgid % 37) * 256, n0 = (wgid / 37) * 128;
  mfma_core_256(A, Wt, DIM, m0, n0, acc, Al, Bl);
  int tid = threadIdx.x, lane = tid & 63, wid = tid >> 6, wr = wid >> 1, wc = wid & 1;
  int ln15 = lane & 15, lq = lane >> 4;
  int colbase = n0 + wc * 64;
  int which = colbase / DIM;
  int rem = colbase - which * DIM;
  int h = rem >> 6;
  __hip_bfloat16* dst = (which == 0) ? q : ((which == 1) ? k : v);
  float fin_scale = (which == 0) ? SCALE : 1.0f;
  float bv[4];
  #pragma unroll
  for (int j = 0; j < 4; j++) bv[j] = bias[colbase + j * 16 + ln15];
  #pragma unroll
  for (int i = 0; i < 4; i++) {
    #pragma unroll
    for (int r = 0; r < 4; r++) {
      int m = m0 + wr * 64 + i * 16 + lq * 4 + r;
      float v4[4];
      #pragma unroll
      for (int j = 0; j < 4; j++) v4[j] = acc[i][j][r] + bv[j];
      float inv = fin_scale;
      if (which < 2) {
        float ss = v4[0]*v4[0] + v4[1]*v4[1] + v4[2]*v4[2] + v4[3]*v4[3];
        ss += __shfl_xor(ss, 1); ss += __shfl_xor(ss, 2);
        ss += __shfl_xor(ss, 4); ss += __shfl_xor(ss, 8);
        inv = rsqrtf(ss * (1.f / 64.f) + 1e-6f) * fin_scale;
      }
      if (m < BATCH * NTOK) {
        int b = m / NTOK, n = m - b * NTOK;
        __hip_bfloat16* orow = dst + (((size_t)b * NH + h) * NTOK + n) * HDIM;
        #pragma unroll
        for (int j = 0; j < 4; j++)
          orow[j * 16 + ln15] = __float2bfloat16(v4[j] * inv);
      }
    }
  }
}

// -------- K6: MFMA flash attention, 128 q-rows, dbuf K/V, T14 reg-split staging --------
__global__ __launch_bounds__(512) void attn_mfma(
    const short* __restrict__ q, const short* __restrict__ k,
    const short* __restrict__ vT, const float* __restrict__ s,
    const float* __restrict__ g, const float* __restrict__ alpha,
    const float* __restrict__ sbs, short* __restrict__ ao) {
  __shared__ short Kh[2][64 * KHS];
  __shared__ short Vt[2][64 * VTS];
  __shared__ short Pl[8][16 * PLS];
  int xcd = blockIdx.x & 7, idx = blockIdx.x >> 3;
  int bh = xcd * 24 + idx / 5;
  int n0 = (idx % 5) * 128;
  int b = bh / NH, h = bh - b * NH;
  int tid = threadIdx.x, lane = tid & 63, w = tid >> 6;
  int l15 = lane & 15, lg = lane >> 4;
  float a = alpha[0], c = a * sbs[0];
  const short* qb = q + (size_t)bh * NTOK * HDIM;
  const short* kb = k + (size_t)bh * NTOK * HDIM;
  const short* vtb = vT + (size_t)bh * HDIM * NTOKP;
  const float* sb = s + (size_t)b * NTOK * SDIM;
  const bf16x8 Z8 = {0, 0, 0, 0, 0, 0, 0, 0};

  int qrow = n0 + w * 16 + l15;
  int qsrc = (qrow < NTOK) ? qrow : 0;
  bf16x8 qf0 = *(const bf16x8*)(qb + (size_t)qsrc * HDIM + lg * 8);
  bf16x8 qf1 = *(const bf16x8*)(qb + (size_t)qsrc * HDIM + 32 + lg * 8);
  bf16x8 qf2 = Z8;
  if (lg < 2) {
    const float* sp = sb + (size_t)qsrc * SDIM + lg * 8;
    #pragma unroll
    for (int j = 0; j < 8; j++) qf2[j] = f2b(c * sp[j]);
  }

  f32x4 accO[4];
  #pragma unroll
  for (int dd = 0; dd < 4; dd++) accO[dd] = (f32x4){0.f, 0.f, 0.f, 0.f};
  float rsum[4] = {0.f, 0.f, 0.f, 0.f};

  int srow = (tid & 255) >> 2, sseg = tid & 3;
  if (tid < 256 && sseg == 3) {   // one-time zero of Khat dims 80..95, both buffers
    #pragma unroll
    for (int bb = 0; bb < 2; bb++) {
      short* dst = Kh[bb] + srow * KHS + 80;
      *(bf16x8*)dst = Z8;
      *(bf16x8*)(dst + 8) = Z8;
    }
  }

  // ---- prologue: stage tile 0 (immediate load+write) ----
  if (tid < 256) {
    int key = srow;
    bool kok = key < NTOK;
    if (sseg < 2) {
      bf16x8 v0 = Z8, v1 = Z8, v2 = Z8, v3 = Z8;
      if (kok) {
        const short* src = kb + (size_t)key * HDIM + sseg * 32;
        v0 = *(const bf16x8*)(src);
        v1 = *(const bf16x8*)(src + 8);
        v2 = *(const bf16x8*)(src + 16);
        v3 = *(const bf16x8*)(src + 24);
      }
      short* dst = Kh[0] + srow * KHS + sseg * 32;
      *(bf16x8*)dst = v0;
      *(bf16x8*)(dst + 8) = v1;
      *(bf16x8*)(dst + 16) = v2;
      *(bf16x8*)(dst + 24) = v3;
    } else if (sseg == 2) {
      bf16x8 v0 = Z8, v1 = Z8;
      if (kok) {
        const float* sp = sb + (size_t)key * SDIM;
        #pragma unroll
        for (int j = 0; j < 8; j++) { v0[j] = f2b(sp[j]); v1[j] = f2b(sp[j + 8]); }
      }
      short* dst = Kh[0] + srow * KHS + 64;
      *(bf16x8*)dst = v0;
      *(bf16x8*)(dst + 8) = v1;
    }
  } else {
    int kk0 = sseg * 16;
    const short* src = vtb + (size_t)srow * NTOKP + kk0;
    short* dst = Vt[0] + srow * VTS + kk0;
    *(bf16x8*)dst = *(const bf16x8*)src;
    *(bf16x8*)(dst + 8) = *(const bf16x8*)(src + 8);
  }
  __syncthreads();

  const int NT = 10;
  for (int ti = 0; ti < NT; ti++) {
    int mt = ti * 64, cur = ti & 1;
    const short* KhC = Kh[cur];
    const short* VtC = Vt[cur];
    bool nxt = (ti + 1 < NT);
    int mtn = mt + 64;
    // ---- T14 stage-load: issue next tile's global loads into registers ----
    bf16x8 kr0 = Z8, kr1 = Z8, kr2 = Z8, kr3 = Z8;
    float4 sf0 = {0,0,0,0}, sf1 = {0,0,0,0}, sf2 = {0,0,0,0}, sf3 = {0,0,0,0};
    if (nxt) {
      if (tid < 256) {
        int key = mtn + srow;
        bool kok = key < NTOK;
        if (sseg < 2) {
          if (kok) {
            const short* src = kb + (size_t)key * HDIM + sseg * 32;
            kr0 = *(const bf16x8*)(src);
            kr1 = *(const bf16x8*)(src + 8);
            kr2 = *(const bf16x8*)(src + 16);
            kr3 = *(const bf16x8*)(src + 24);
          }
        } else if (sseg == 2) {
          if (kok) {
            const float* sp = sb + (size_t)key * SDIM;
            sf0 = *(const float4*)(sp);
            sf1 = *(const float4*)(sp + 4);
            sf2 = *(const float4*)(sp + 8);
            sf3 = *(const float4*)(sp + 12);
          }
        }
      } else {
        // V: unguarded 16B loads; overrun keys get P==0 so any finite value is safe
        int kk0 = sseg * 16;
        const short* src = vtb + (size_t)srow * NTOKP + mtn + kk0;
        kr0 = *(const bf16x8*)src;
        kr1 = *(const bf16x8*)(src + 8);
      }
    }
    // ---- QK from Kh[cur] (hides the in-flight loads) ----
    f32x4 sa[4];
    __builtin_amdgcn_s_setprio(1);
    #pragma unroll
    for (int jj = 0; jj < 4; jj++) {
      sa[jj] = (f32x4){0.f, 0.f, 0.f, 0.f};
      const short* kp = KhC + (jj * 16 + l15) * KHS + lg * 8;
      sa[jj] = __builtin_amdgcn_mfma_f32_16x16x32_bf16(qf0, *(const bf16x8*)kp, sa[jj], 0, 0, 0);
      sa[jj] = __builtin_amdgcn_mfma_f32_16x16x32_bf16(qf1, *(const bf16x8*)(kp + 32), sa[jj], 0, 0, 0);
      sa[jj] = __builtin_amdgcn_mfma_f32_16x16x32_bf16(qf2, *(const bf16x8*)(kp + 64), sa[jj], 0, 0, 0);
    }
    __builtin_amdgcn_s_setprio(0);
    // ---- T14 stage-write: registers -> buf[cur^1] (race-free: other buffer) ----
    if (nxt) {
      if (tid < 256) {
        if (sseg < 2) {
          short* dst = Kh[cur ^ 1] + srow * KHS + sseg * 32;
          *(bf16x8*)dst = kr0;
          *(bf16x8*)(dst + 8) = kr1;
          *(bf16x8*)(dst + 16) = kr2;
          *(bf16x8*)(dst + 24) = kr3;
        } else if (sseg == 2) {
          bf16x8 v0, v1;
          v0[0] = f2b(sf0.x); v0[1] = f2b(sf0.y); v0[2] = f2b(sf0.z); v0[3] = f2b(sf0.w);
          v0[4] = f2b(sf1.x); v0[5] = f2b(sf1.y); v0[6] = f2b(sf1.z); v0[7] = f2b(sf1.w);
          v1[0] = f2b(sf2.x); v1[1] = f2b(sf2.y); v1[2] = f2b(sf2.z); v1[3] = f2b(sf2.w);
          v1[4] = f2b(sf3.x); v1[5] = f2b(sf3.y); v1[6] = f2b(sf3.z); v1[7] = f2b(sf3.w);
          short* dst = Kh[cur ^ 1] + srow * KHS + 64;
          *(bf16x8*)dst = v0;
          *(bf16x8*)(dst + 8) = v1;
        }
      } else {
        int kk0 = sseg * 16;
        short* dst = Vt[cur ^ 1] + srow * VTS + kk0;
        *(bf16x8*)dst = kr0;
        *(bf16x8*)(dst + 8) = kr1;
      }
    }
    // ---- softmax -> Pl ----
    short* pw = Pl[w];
    float ps[4][4];
    #pragma unroll
    for (int jj = 0; jj < 4; jj++) {
      bool ok = (mt + jj * 16 + l15) < NTOK;
      #pragma unroll
      for (int r = 0; r < 4; r++) {
        float x = sa[jj][r];
        x = fminf(fmaxf(x, -CLIPV), CLIPV);
        float e = ok ? __expf(x) : 0.f;
        ps[jj][r] = e;
        pw[(lg * 4 + r) * PLS + jj * 16 + l15] = f2b(e);
      }
    }
    #pragma unroll
    for (int r = 0; r < 4; r++) {
      float t = ps[0][r] + ps[1][r] + ps[2][r] + ps[3][r];
      t += __shfl_xor(t, 1); t += __shfl_xor(t, 2);
      t += __shfl_xor(t, 4); t += __shfl_xor(t, 8);
      rsum[r] += t;
    }
    // ---- PV from Vt[cur] ----
    __builtin_amdgcn_s_setprio(1);
    #pragma unroll
    for (int kc = 0; kc < 2; kc++) {
      bf16x8 pa = *(const bf16x8*)(pw + l15 * PLS + kc * 32 + lg * 8);
      #pragma unroll
      for (int dd = 0; dd < 4; dd++) {
        bf16x8 vf = *(const bf16x8*)(VtC + (dd * 16 + l15) * VTS + kc * 32 + lg * 8);
        accO[dd] = __builtin_amdgcn_mfma_f32_16x16x32_bf16(pa, vf, accO[dd], 0, 0, 0);
      }
    }
    __builtin_amdgcn_s_setprio(0);
    __syncthreads();   // next-tile buffers fully written for all waves
  }
  float gm = 1.f + a * g[bh];
  #pragma unroll
  for (int r = 0; r < 4; r++) {
    int n = n0 + w * 16 + lg * 4 + r;
    if (n >= NTOK) continue;
    float inv = gm / rsum[r];
    short* orow = ao + ((size_t)b * NTOK + n) * DIM + h * HDIM;
    #pragma unroll
    for (int dd = 0; dd < 4; dd++)
      orow[dd * 16 + l15] = f2b(accO[dd][r] * inv);
  }
}

// -------- K7: proj GEMM (64x128 counted, n-major) + residual --------
__global__ __launch_bounds__(256) void gemm_proj(
    const short* __restrict__ A, const short* __restrict__ Wt, const float* __restrict__ bias,
    float* __restrict__ xw, float* __restrict__ out) {
  __shared__ short Al0[64 * 64], Bl0[128 * 64], Al1[64 * 64], Bl1[128 * 64];
  f32x4 acc[4][2];
  int wgid = swz_wgid(blockIdx.x, 145 * 6);
  int m0 = (wgid % 145) * 64, n0 = (wgid / 145) * 128;
  mfma_core_64(A, Wt, DIM, m0, n0, acc, Al0, Bl0, Al1, Bl1);
  int tid = threadIdx.x, lane = tid & 63, wid = tid >> 6;
  int ln15 = lane & 15, lq = lane >> 4;
  #pragma unroll
  for (int i = 0; i < 4; i++) {
    #pragma unroll
    for (int j = 0; j < 2; j++) {
      int col = n0 + wid * 32 + j * 16 + ln15;
      float bv = bias[col];
      #pragma unroll
      for (int r = 0; r < 4; r++) {
        int m = m0 + i * 16 + lq * 4 + r;
        if (m >= BATCH * NTOK) continue;
        int n = m % NTOK;
        float val = acc[i][j][r] + bv + xw[(size_t)m * DIM + col];
        xw[(size_t)m * DIM + col] = val;
        if (n < 2) out[(size_t)m * DIM + col] = val;
      }
    }
  }
}

// -------- K8: LN for MLP -> xm bf16 --------
__global__ __launch_bounds__(256) void ln_mlp_kernel(
    const float* __restrict__ x2, const float* __restrict__ w, const float* __restrict__ bb,
    __hip_bfloat16* __restrict__ xm) {
  int r = blockIdx.x;
  int b = r / NP, pi = r % NP;
  int tid = threadIdx.x;
  const float* xr = x2 + ((size_t)b * NTOK + 2 + pi) * DIM;
  float vals[3];
  #pragma unroll
  for (int j = 0; j < 3; j++) vals[j] = xr[tid + j * 256];
  float s = vals[0] + vals[1] + vals[2];
  float ss = vals[0]*vals[0] + vals[1]*vals[1] + vals[2]*vals[2];
  block_reduce2(s, ss);
  float mean = s * (1.f / 768.f);
  float inv = rsqrtf(ss * (1.f / 768.f) - mean * mean + 1e-6f);
  __hip_bfloat16* xo = xm + (size_t)r * DIM;
  #pragma unroll
  for (int j = 0; j < 3; j++) {
    int d = tid + j * 256;
    xo[d] = __float2bfloat16((vals[j] - mean) * inv * w[d] + bb[d]);
  }
}

// -------- K9: fc1 GEMM (256x128 n-major, chunk) + GELU --------
__global__ __launch_bounds__(512) void gemm_fc1(
    const short* __restrict__ A, const short* __restrict__ Wt, const float* __restrict__ bias,
    __hip_bfloat16* __restrict__ h1) {
  __shared__ short Al[256 * 64], Bl[128 * 64];
  f32x4 acc[4][4];
  int wgid = swz_wgid(blockIdx.x, 18 * 24);
  int m0 = (wgid % 18) * 256, n0 = (wgid / 18) * 128;
  mfma_core_256(A, Wt, DIM, m0, n0, acc, Al, Bl);
  int tid = threadIdx.x, lane = tid & 63, wid = tid >> 6, wr = wid >> 1, wc = wid & 1;
  int ln15 = lane & 15, lq = lane >> 4;
  #pragma unroll
  for (int i = 0; i < 4; i++) {
    #pragma unroll
    for (int j = 0; j < 4; j++) {
      int col = n0 + wc * 64 + j * 16 + ln15;
      float bv = bias[col];
      #pragma unroll
      for (int r = 0; r < 4; r++) {
        int m = m0 + wr * 64 + i * 16 + lq * 4 + r;
        float val = acc[i][j][r] + bv;
        float ge = 0.5f * val * (1.f + erff(val * 0.70710678118f));
        h1[(size_t)m * HID + col] = __float2bfloat16(ge);
      }
    }
  }
}

// -------- K10: depthwise 3x3 conv + SiLU --------
__global__ __launch_bounds__(256) void dwconv_kernel(
    const __hip_bfloat16* __restrict__ h1, const float* __restrict__ dwt,
    const float* __restrict__ dwb, __hip_bfloat16* __restrict__ h2) {
  int gx = blockIdx.x;
  int b = gx / 144, g = gx - b * 144;
  int y = g / 6, x0 = (g - y * 6) * 4;
  int tid = threadIdx.x;
  int c0 = blockIdx.y * 512 + (tid & 63) * 8;
  int x = x0 + (tid >> 6);
  const short* in = (const short*)h1 + (size_t)b * NP * HID + c0;
  bf16x8 iv[3][3];
  #pragma unroll
  for (int ky = 0; ky < 3; ky++) {
    int yy = y + ky - 1;
    #pragma unroll
    for (int kx = 0; kx < 3; kx++) {
      int xx = x + kx - 1;
      bool ok = (yy >= 0 && yy < PGRID && xx >= 0 && xx < PGRID);
      iv[ky][kx] = ok ? *(const bf16x8*)(in + (size_t)(yy * PGRID + xx) * HID)
                      : (bf16x8){0, 0, 0, 0, 0, 0, 0, 0};
    }
  }
  float acc[8];
  {
    float4 b0 = *(const float4*)(dwb + c0);
    float4 b1 = *(const float4*)(dwb + c0 + 4);
    acc[0] = b0.x; acc[1] = b0.y; acc[2] = b0.z; acc[3] = b0.w;
    acc[4] = b1.x; acc[5] = b1.y; acc[6] = b1.z; acc[7] = b1.w;
  }
  #pragma unroll
  for (int t = 0; t < 9; t++) {
    float4 w0 = *(const float4*)(dwt + t * HID + c0);
    float4 w1 = *(const float4*)(dwt + t * HID + c0 + 4);
    bf16x8 xv = iv[t / 3][t % 3];
    acc[0] += b2f(xv[0]) * w0.x; acc[1] += b2f(xv[1]) * w0.y;
    acc[2] += b2f(xv[2]) * w0.z; acc[3] += b2f(xv[3]) * w0.w;
    acc[4] += b2f(xv[4]) * w1.x; acc[5] += b2f(xv[5]) * w1.y;
    acc[6] += b2f(xv[6]) * w1.z; acc[7] += b2f(xv[7]) * w1.w;
  }
  short ov[8];
  #pragma unroll
  for (int e = 0; e < 8; e++) {
    float v = acc[e];
    ov[e] = f2b(v / (1.f + __expf(-v)));
  }
  *(bf16x8*)((short*)h2 + ((size_t)b * NP + y * PGRID + x) * HID + c0) = *(bf16x8*)ov;
}

// -------- K11: fc2 GEMM (64x128 counted, n-major, chunk) + residual --------
__global__ __launch_bounds__(256) void gemm_fc2(
    const short* __restrict__ A, const short* __restrict__ Wt, const float* __restrict__ bias,
    const float* __restrict__ xw, float* __restrict__ out, int b0) {
  __shared__ short Al0[64 * 64], Bl0[128 * 64], Al1[64 * 64], Bl1[128 * 64];
  f32x4 acc[4][2];
  int wgid = swz_wgid(blockIdx.x, 72 * 6);
  int m0 = (wgid % 72) * 64, n0 = (wgid / 72) * 128;
  mfma_core_64(A, Wt, HID, m0, n0, acc, Al0, Bl0, Al1, Bl1);
  int tid = threadIdx.x, lane = tid & 63, wid = tid >> 6;
  int ln15 = lane & 15, lq = lane >> 4;
  #pragma unroll
  for (int i = 0; i < 4; i++) {
    #pragma unroll
    for (int j = 0; j < 2; j++) {
      int col = n0 + wid * 32 + j * 16 + ln15;
      float bv = bias[col];
      #pragma unroll
      for (int r = 0; r < 4; r++) {
        int m = m0 + i * 16 + lq * 4 + r;
        int bl = m / NP, pi = m - bl * NP;
        size_t orow = ((size_t)(b0 + bl) * NTOK + 2 + pi) * DIM;
        out[orow + col] = acc[i][j][r] + bv + xw[orow + col];
      }
    }
  }
}

extern "C" void kernel_launch(void* const* d_in, const int* in_sizes, int n_in,
                              void* d_out, int out_size, void* d_ws, size_t ws_size,
                              hipStream_t stream) {
  const float* x      = (const float*)d_in[0];
  const float* ftc    = (const float*)d_in[2];
  const float* fsum   = (const float*)d_in[3];
  const float* tbf    = (const float*)d_in[4];
  const float* alpha  = (const float*)d_in[5];
  const float* lgw    = (const float*)d_in[6];
  const float* lgb    = (const float*)d_in[7];
  const float* film_w = (const float*)d_in[8];
  const float* film_b = (const float*)d_in[9];
  const float* law    = (const float*)d_in[10];
  const float* lab    = (const float*)d_in[11];
  const float* qkv_w  = (const float*)d_in[12];
  const float* qkv_b  = (const float*)d_in[13];
  const float* proj_w = (const float*)d_in[14];
  const float* proj_b = (const float*)d_in[15];
  const float* sbs    = (const float*)d_in[16];
  const float* gate_w = (const float*)d_in[17];
  const float* gate_b = (const float*)d_in[18];
  const float* band_w = (const float*)d_in[19];
  const float* lmw    = (const float*)d_in[20];
  const float* lmb    = (const float*)d_in[21];
  const float* fc1_w  = (const float*)d_in[22];
  const float* fc1_b  = (const float*)d_in[23];
  const float* fc2_w  = (const float*)d_in[24];
  const float* fc2_b  = (const float*)d_in[25];
  const float* dw_w   = (const float*)d_in[26];
  const float* dw_b   = (const float*)d_in[27];
  float* out = (float*)d_out;

  float* ws = (float*)d_ws;
  const size_t SZ = (size_t)BATCH * NTOK * DIM;  // 7,102,464

  float* p_xw = ws;
  short* p_xn = (short*)(ws + SZ);
  short* p_q  = (short*)(ws + SZ + SZ / 2);
  short* p_k  = (short*)(ws + 2 * SZ);
  short* p_v  = (short*)(ws + 2 * SZ + SZ / 2);
  float* p_s  = ws + 3 * SZ;
  float* p_gamma = p_s + (size_t)BATCH * NTOK * SDIM;
  float* p_beta  = p_gamma + BATCH * DIM;
  float* p_g     = p_beta + BATCH * DIM;
  float* p_dwt   = p_g + 256;
  float* p_part  = p_dwt + 9 * HID;
  float* wtb = p_part + (size_t)FKS * BATCH * 1536;
  short* qkvT = (short*)wtb;
  short* projT = qkvT + (size_t)768 * 2304;
  short* fc1T  = projT + (size_t)768 * 768;
  short* fc2T  = fc1T + (size_t)768 * 3072;
  short* h2c   = fc2T + (size_t)3072 * 768;

  const size_t total_floats =
      3 * SZ + (size_t)BATCH * NTOK * SDIM + 2 * (size_t)BATCH * DIM + 256 + 9 * HID +
      (size_t)FKS * BATCH * 1536 +
      ((size_t)768 * 2304 + 768 * 768 + 768 * 3072 + 3072 * 768) / 2 +
      ((size_t)8 * NP * HID) / 2;
  if (ws_size < total_floats * sizeof(float)) return;

  short* p_ao = p_xn;
  short* p_xm = p_q;
  short* h1c  = p_k;
  short* p_vT = h2c;

  dim3 blk(256);

  prep_weights<<<dim3(432 + 108), blk, 0, stream>>>(
      qkv_w, proj_w, fc1_w, fc2_w, dw_w, qkvT, projT, fc1T, fc2T, p_dwt);

  film_part<<<dim3(12 * FKS), blk, 0, stream>>>(fsum, film_w, p_part);

  film_fin<<<dim3(96 + 48), blk, 0, stream>>>(
      p_part, film_b, ftc, gate_w, gate_b, p_gamma, p_beta, p_g);

  band_s_kernel<<<dim3((BATCH * NTOK + 3) / 4), blk, 0, stream>>>(tbf, band_w, p_s);

  ln_film_kernel<<<dim3(BATCH * NTOK), blk, 0, stream>>>(
      x, p_gamma, p_beta, lgw, lgb, law, lab, alpha, p_xw, (__hip_bfloat16*)p_xn);

  gemm_qkv<<<dim3(37 * 18), dim3(512), 0, stream>>>(
      p_xn, qkvT, qkv_b, (__hip_bfloat16*)p_q, (__hip_bfloat16*)p_k, (__hip_bfloat16*)p_v);

  transpose_v<<<dim3(10, BATCH * NH), blk, 0, stream>>>(p_v, p_vT);

  attn_mfma<<<dim3(960), dim3(512), 0, stream>>>(
      p_q, p_k, p_vT, p_s, p_g, alpha, sbs, p_ao);

  gemm_proj<<<dim3(145 * 6), blk, 0, stream>>>(p_ao, projT, proj_b, p_xw, out);

  ln_mlp_kernel<<<dim3(BATCH * NP), blk, 0, stream>>>(p_xw, lmw, lmb, (__hip_bfloat16*)p_xm);

  for (int cc = 0; cc < 2; cc++) {
    const short* Ach = p_xm + (size_t)cc * 4608 * DIM;
    gemm_fc1<<<dim3(18 * 24), dim3(512), 0, stream>>>(Ach, fc1T, fc1_b, (__hip_bfloat16*)h1c);
    dwconv_kernel<<<dim3(8 * 144, 6), blk, 0, stream>>>(
        (const __hip_bfloat16*)h1c, p_dwt, dw_b, (__hip_bfloat16*)h2c);
    gemm_fc2<<<dim3(72 * 6), blk, 0, stream>>>(h2c, fc2T, fc2_b, p_xw, out, cc * 8);
  }
}

// Round 20
// 427.532 us; speedup vs baseline: 1.0516x; 1.0257x over previous
//
#include <hip/hip_runtime.h>
#include <hip/hip_bf16.h>

#define BATCH 16
#define NTOK 578
#define NTOKP 592
#define NP 576
#define PGRID 24
#define DIM 768
#define NH 12
#define HDIM 64
#define BAND 64
#define SDIM 16
#define HID 3072
#define SCALE 0.125f
#define CLIPV 10.0f
#define KHS 104
#define VTS 72
#define PLS 72
#define FKS 16   // film k-splits

typedef __attribute__((ext_vector_type(8))) short bf16x8;
typedef __attribute__((ext_vector_type(4))) float f32x4;

__device__ __forceinline__ float b2f(short u) {
  union { float f; unsigned int i; } x;
  x.i = ((unsigned int)(unsigned short)u) << 16;
  return x.f;
}
__device__ __forceinline__ short f2b(float x) {
  __hip_bfloat16 h = __float2bfloat16(x);
  return *reinterpret_cast<short*>(&h);
}

__device__ __forceinline__ void gload16(const short* g, short* l) {
  __builtin_amdgcn_global_load_lds(
      (const __attribute__((address_space(1))) unsigned int*)g,
      (__attribute__((address_space(3))) unsigned int*)l, 16, 0, 0);
}

// bijective XCD-chunk swizzle (m204)
__device__ __forceinline__ int swz_wgid(int orig, int nwg) {
  int xcd = orig & 7, i = orig >> 3;
  int q = nwg >> 3, r = nwg & 7;
  return (xcd < r) ? xcd * (q + 1) + i : r * (q + 1) + (xcd - r) * q + i;
}

__device__ __forceinline__ void block_reduce2(float& a, float& b) {
  __shared__ float sm[8];
  #pragma unroll
  for (int o = 32; o > 0; o >>= 1) { a += __shfl_down(a, o); b += __shfl_down(b, o); }
  int lane = threadIdx.x & 63, w = threadIdx.x >> 6;
  __syncthreads();
  if (lane == 0) { sm[w] = a; sm[4 + w] = b; }
  __syncthreads();
  a = sm[0] + sm[1] + sm[2] + sm[3];
  b = sm[4] + sm[5] + sm[6] + sm[7];
}

// -------- transpose: 256(k) x 64(n) tile --------
#define TKS 266
__device__ __forceinline__ void tw2(
    const float* __restrict__ W, short* __restrict__ Wt, int K, int N,
    int kblk, int nblk, short* t) {
  int tid = threadIdx.x;
  int k0 = kblk * 256, n0 = nblk * 64;
  int r0 = tid >> 4, c0 = (tid & 15) * 4;
  #pragma unroll
  for (int it = 0; it < 16; it++) {
    int r = it * 16 + r0;
    float4 v = *(const float4*)(W + (size_t)(k0 + r) * N + n0 + c0);
    t[(c0 + 0) * TKS + r] = f2b(v.x);
    t[(c0 + 1) * TKS + r] = f2b(v.y);
    t[(c0 + 2) * TKS + r] = f2b(v.z);
    t[(c0 + 3) * TKS + r] = f2b(v.w);
  }
  __syncthreads();
  int n1 = tid >> 5, k1 = (tid & 31) * 8;
  #pragma unroll
  for (int it = 0; it < 8; it++) {
    int n = it * 8 + n1;
    *(bf16x8*)(Wt + (size_t)(n0 + n) * K + k0 + k1) = *(bf16x8*)(t + n * TKS + k1);
  }
}

// -------- fused prologue: 4 transposes + dwt + film_part + band_s --------
// Blocks: [0,108) qkvT, [108,144) projT, [144,288) fc1T, [288,432) fc2T,
//         [432,540) dwt, [540,732) film_part, [732,1310) band_s.
__global__ __launch_bounds__(256) void prologue_kernel(
    const float* __restrict__ qkv_w, const float* __restrict__ proj_w,
    const float* __restrict__ fc1_w, const float* __restrict__ fc2_w,
    const float* __restrict__ dww,
    const float* __restrict__ fsum, const float* __restrict__ film_w,
    const float* __restrict__ tbf, const float* __restrict__ band_w,
    short* __restrict__ qkvT, short* __restrict__ projT,
    short* __restrict__ fc1T, short* __restrict__ fc2T,
    float* __restrict__ dwt, float* __restrict__ part, float* __restrict__ s) {
  __shared__ short t[64 * TKS];   // 34KB; film branch reuses as float fs[16][48]
  int id = blockIdx.x, tid = threadIdx.x;
  if (id < 108) {
    tw2(qkv_w, qkvT, 768, 2304, id % 3, id / 3, t);
  } else if (id < 144) {
    int u = id - 108; tw2(proj_w, projT, 768, 768, u % 3, u / 3, t);
  } else if (id < 288) {
    int u = id - 144; tw2(fc1_w, fc1T, 768, 3072, u % 3, u / 3, t);
  } else if (id < 432) {
    int u = id - 288; tw2(fc2_w, fc2T, 3072, 768, u % 12, u / 12, t);
  } else if (id < 540) {
    int i = (id - 432) * 256 + tid;
    if (i < 9 * HID) { int tt = i / HID, c = i - tt * HID; dwt[i] = dww[c * 9 + tt]; }
  } else if (id < 732) {
    // film_part: k-split partials
    float (*fs)[48] = (float(*)[48])t;
    int bid = id - 540;
    int cg = bid % 12, ks = bid / 12;
    int k0 = ks * 48;
    for (int i = tid; i < BATCH * 48; i += 256) {
      int b = i / 48, kk = i - b * 48;
      fs[b][kk] = fsum[b * DIM + k0 + kk];
    }
    __syncthreads();
    int col4 = cg * 128 + (tid & 31) * 4;
    int bq = tid >> 5;
    float a0[4] = {0.f, 0.f, 0.f, 0.f}, a1[4] = {0.f, 0.f, 0.f, 0.f};
    #pragma unroll 4
    for (int kk = 0; kk < 48; kk++) {
      float4 w = *(const float4*)(film_w + (size_t)(k0 + kk) * 2 * DIM + col4);
      float f0 = fs[bq][kk], f1 = fs[bq + 8][kk];
      a0[0] += f0 * w.x; a0[1] += f0 * w.y; a0[2] += f0 * w.z; a0[3] += f0 * w.w;
      a1[0] += f1 * w.x; a1[1] += f1 * w.y; a1[2] += f1 * w.z; a1[3] += f1 * w.w;
    }
    *(float4*)(part + ((size_t)ks * BATCH + bq) * 1536 + col4) =
        (float4){a0[0], a0[1], a0[2], a0[3]};
    *(float4*)(part + ((size_t)ks * BATCH + bq + 8) * 1536 + col4) =
        (float4){a1[0], a1[1], a1[2], a1[3]};
  } else {
    // band_s: all 64 lanes used; 16 rows/block (9248 = 578*16)
    int row = (id - 732) * 16 + (tid >> 4);
    int col = tid & 15;
    if (row < BATCH * NTOK) {
      const float* tb = tbf + (size_t)row * BAND;
      float val = 0.f;
      #pragma unroll 4
      for (int i = 0; i < BAND; i++) val += tb[i] * band_w[i * SDIM + col];
      float ss = val * val;
      #pragma unroll
      for (int o = 8; o > 0; o >>= 1) ss += __shfl_xor(ss, o, 16);
      s[(size_t)row * SDIM + col] = val * rsqrtf(ss * (1.f / 16.f) + 1e-6f);
    }
  }
}

// -------- FiLM stage 2 + gate GEMV --------
__global__ __launch_bounds__(256) void film_fin(
    const float* __restrict__ part, const float* __restrict__ film_b,
    const float* __restrict__ ftc, const float* __restrict__ gate_w,
    const float* __restrict__ gate_b,
    float* __restrict__ gamma, float* __restrict__ beta, float* __restrict__ g) {
  int bid = blockIdx.x;
  if (bid < 96) {
    int idx = bid * 256 + threadIdx.x;
    int b = idx / 1536, col = idx - b * 1536;
    float acc = film_b[col];
    #pragma unroll
    for (int ks = 0; ks < FKS; ks++)
      acc += part[((size_t)ks * BATCH + b) * 1536 + col];
    float t = tanhf(acc) * 0.5f;
    if (col < DIM) gamma[b * DIM + col] = t;
    else beta[b * DIM + (col - DIM)] = t;
  } else {
    int widx = (bid - 96) * 4 + (threadIdx.x >> 6);
    int lane = threadIdx.x & 63;
    if (widx < BATCH * NH) {
      int b = widx / NH, h = widx - b * NH;
      float acc = 0.f;
      for (int kk = lane; kk < DIM; kk += 64) acc += ftc[b * DIM + kk] * gate_w[kk * NH + h];
      #pragma unroll
      for (int o = 32; o > 0; o >>= 1) acc += __shfl_down(acc, o);
      if (lane == 0) g[widx] = tanhf(acc + gate_b[h]) * 0.05f;
    }
  }
}

// -------- v -> vT --------
__global__ __launch_bounds__(256) void transpose_v(
    const short* __restrict__ v, short* __restrict__ vT) {
  __shared__ short t[64][72];
  int bh = blockIdx.y;
  int n0 = blockIdx.x * 64;
  int tid = threadIdx.x;
  const short* vb = v + (size_t)bh * NTOK * HDIM;
  short* ob = vT + (size_t)bh * HDIM * NTOKP;
  {
    int r = tid >> 2, c0 = (tid & 3) * 16;
    int n = n0 + r;
    bf16x8 a0 = {0,0,0,0,0,0,0,0}, a1 = {0,0,0,0,0,0,0,0};
    if (n < NTOK) {
      a0 = *(const bf16x8*)(vb + (size_t)n * HDIM + c0);
      a1 = *(const bf16x8*)(vb + (size_t)n * HDIM + c0 + 8);
    }
    *(bf16x8*)(&t[r][c0]) = a0;
    *(bf16x8*)(&t[r][c0 + 8]) = a1;
  }
  __syncthreads();
  {
    int d = tid & 63, nc = tid >> 6;
    int nbase = n0 + nc * 16;
    short tmp[16];
    #pragma unroll
    for (int e = 0; e < 16; e++) tmp[e] = t[nc * 16 + e][d];
    if (nbase + 16 <= NTOK) {
      *(bf16x8*)(ob + (size_t)d * NTOKP + nbase) = *(bf16x8*)tmp;
      *(bf16x8*)(ob + (size_t)d * NTOKP + nbase + 8) = *(bf16x8*)(tmp + 8);
    } else {
      for (int e = 0; e < 16; e++)
        if (nbase + e < NTOK) ob[(size_t)d * NTOKP + nbase + e] = tmp[e];
    }
  }
}

// -------- LN(gate)+FiLM -> xw ; LN(attn) -> xn --------
__global__ __launch_bounds__(256) void ln_film_kernel(
    const float* __restrict__ x, const float* __restrict__ gamma, const float* __restrict__ beta,
    const float* __restrict__ gw, const float* __restrict__ gb,
    const float* __restrict__ aw, const float* __restrict__ ab,
    const float* __restrict__ alpha, float* __restrict__ xw, __hip_bfloat16* __restrict__ xn) {
  int row = blockIdx.x;
  int b = row / NTOK, n = row % NTOK;
  int tid = threadIdx.x;
  const float* xr = x + (size_t)row * DIM;
  float vals[3];
  #pragma unroll
  for (int j = 0; j < 3; j++) vals[j] = xr[tid + j * 256];
  if (n >= 2) {
    float s = vals[0] + vals[1] + vals[2];
    float ss = vals[0]*vals[0] + vals[1]*vals[1] + vals[2]*vals[2];
    block_reduce2(s, ss);
    float mean = s * (1.f / 768.f);
    float inv = rsqrtf(ss * (1.f / 768.f) - mean * mean + 1e-6f);
    float a = alpha[0];
    #pragma unroll
    for (int j = 0; j < 3; j++) {
      int d = tid + j * 256;
      float p = (vals[j] - mean) * inv * gw[d] + gb[d];
      vals[j] = p * (1.f + a * gamma[(size_t)b * DIM + d]) + a * beta[(size_t)b * DIM + d];
    }
  }
  float* xwr = xw + (size_t)row * DIM;
  #pragma unroll
  for (int j = 0; j < 3; j++) xwr[tid + j * 256] = vals[j];
  float s = vals[0] + vals[1] + vals[2];
  float ss = vals[0]*vals[0] + vals[1]*vals[1] + vals[2]*vals[2];
  block_reduce2(s, ss);
  float mean = s * (1.f / 768.f);
  float inv = rsqrtf(ss * (1.f / 768.f) - mean * mean + 1e-6f);
  __hip_bfloat16* xnr = xn + (size_t)row * DIM;
  #pragma unroll
  for (int j = 0; j < 3; j++) {
    int d = tid + j * 256;
    xnr[d] = __float2bfloat16((vals[j] - mean) * inv * aw[d] + ab[d]);
  }
}

// ======== 256x128 MFMA core (single buffer, XOR-swizzled LDS) ========
__device__ __forceinline__ void stage_tile256(
    const short* __restrict__ A, const short* __restrict__ Wt, int K,
    int m0, int n0, int kt, short* Al, short* Bl, int wid, int lrow, int lcolsw) {
  #pragma unroll
  for (int it = 0; it < 4; it++) {
    int r0 = wid * 8 + it * 64;
    gload16(A + (size_t)(m0 + r0 + lrow) * K + kt + lcolsw, Al + r0 * 64);
  }
  #pragma unroll
  for (int it = 0; it < 2; it++) {
    int r0 = wid * 8 + it * 64;
    gload16(Wt + (size_t)(n0 + r0 + lrow) * K + kt + lcolsw, Bl + r0 * 64);
  }
}

__device__ __forceinline__ void compute_tile256(
    const short* Al, const short* Bl, f32x4 acc[4][4],
    int wr, int wc, int ln15, int kb) {
  int rx = ln15 & 7;
  #pragma unroll
  for (int kk = 0; kk < 2; kk++) {
    int csw = ((kk * 4 + kb) ^ rx) * 8;
    bf16x8 af[4], bfr[4];
    #pragma unroll
    for (int i = 0; i < 4; i++)
      af[i] = *(const bf16x8*)(Al + (wr * 64 + i * 16 + ln15) * 64 + csw);
    #pragma unroll
    for (int j = 0; j < 4; j++)
      bfr[j] = *(const bf16x8*)(Bl + (wc * 64 + j * 16 + ln15) * 64 + csw);
    #pragma unroll
    for (int i = 0; i < 4; i++)
      #pragma unroll
      for (int j = 0; j < 4; j++)
        acc[i][j] = __builtin_amdgcn_mfma_f32_16x16x32_bf16(af[i], bfr[j], acc[i][j], 0, 0, 0);
  }
}

__device__ __forceinline__ void mfma_core_256(
    const short* __restrict__ A, const short* __restrict__ Wt,
    int K, int m0, int n0, f32x4 acc[4][4], short* Al, short* Bl) {
  int tid = threadIdx.x, lane = tid & 63, wid = tid >> 6;
  int wr = wid >> 1, wc = wid & 1;
  int ln15 = lane & 15, kb = lane >> 4;
  int lrow = lane >> 3;
  int lcolsw = (((lane & 7) ^ lrow) & 7) * 8;
  #pragma unroll
  for (int i = 0; i < 4; i++)
    #pragma unroll
    for (int j = 0; j < 4; j++) acc[i][j] = (f32x4){0.f, 0.f, 0.f, 0.f};
  for (int kt = 0; kt < K; kt += 64) {
    stage_tile256(A, Wt, K, m0, n0, kt, Al, Bl, wid, lrow, lcolsw);
    __syncthreads();
    compute_tile256(Al, Bl, acc, wr, wc, ln15, kb);
    __syncthreads();
  }
}

// ======== 64x128 MFMA core (counted-vmcnt dbuf, XOR-swizzled) ========
__device__ __forceinline__ void stage_tile64(
    const short* __restrict__ A, const short* __restrict__ Wt, int K,
    int m0, int n0, int kt, short* Al, short* Bl, int wid, int lrow, int lcolsw) {
  #pragma unroll
  for (int it = 0; it < 2; it++) {
    int r0 = wid * 8 + it * 32;
    gload16(A + (size_t)(m0 + r0 + lrow) * K + kt + lcolsw, Al + r0 * 64);
  }
  #pragma unroll
  for (int it = 0; it < 4; it++) {
    int r0 = wid * 8 + it * 32;
    gload16(Wt + (size_t)(n0 + r0 + lrow) * K + kt + lcolsw, Bl + r0 * 64);
  }
}

__device__ __forceinline__ void compute_tile64(
    const short* Al, const short* Bl, f32x4 acc[4][2],
    int wid, int ln15, int kb) {
  int rx = ln15 & 7;
  #pragma unroll
  for (int kk = 0; kk < 2; kk++) {
    int csw = ((kk * 4 + kb) ^ rx) * 8;
    bf16x8 af[4], bfr[2];
    #pragma unroll
    for (int i = 0; i < 4; i++)
      af[i] = *(const bf16x8*)(Al + (i * 16 + ln15) * 64 + csw);
    #pragma unroll
    for (int j = 0; j < 2; j++)
      bfr[j] = *(const bf16x8*)(Bl + (wid * 32 + j * 16 + ln15) * 64 + csw);
    #pragma unroll
    for (int i = 0; i < 4; i++)
      #pragma unroll
      for (int j = 0; j < 2; j++)
        acc[i][j] = __builtin_amdgcn_mfma_f32_16x16x32_bf16(af[i], bfr[j], acc[i][j], 0, 0, 0);
  }
}

__device__ __forceinline__ void mfma_core_64(
    const short* __restrict__ A, const short* __restrict__ Wt,
    int K, int m0, int n0, f32x4 acc[4][2],
    short* Al0, short* Bl0, short* Al1, short* Bl1) {
  int tid = threadIdx.x, lane = tid & 63, wid = tid >> 6;
  int ln15 = lane & 15, kb = lane >> 4;
  int lrow = lane >> 3;
  int lcolsw = (((lane & 7) ^ lrow) & 7) * 8;
  #pragma unroll
  for (int i = 0; i < 4; i++)
    #pragma unroll
    for (int j = 0; j < 2; j++) acc[i][j] = (f32x4){0.f, 0.f, 0.f, 0.f};
  stage_tile64(A, Wt, K, m0, n0, 0, Al0, Bl0, wid, lrow, lcolsw);
  stage_tile64(A, Wt, K, m0, n0, 64, Al1, Bl1, wid, lrow, lcolsw);
  asm volatile("s_waitcnt vmcnt(6)" ::: "memory");
  __builtin_amdgcn_s_barrier();
  const int NKT = K >> 6;
  for (int t = 0; t < NKT; t++) {
    const short* Ac = (t & 1) ? Al1 : Al0;
    const short* Bc = (t & 1) ? Bl1 : Bl0;
    compute_tile64(Ac, Bc, acc, wid, ln15, kb);
    __builtin_amdgcn_s_barrier();
    if (t + 2 < NKT) {
      short* As = (t & 1) ? Al1 : Al0;
      short* Bs = (t & 1) ? Bl1 : Bl0;
      stage_tile64(A, Wt, K, m0, n0, (t + 2) << 6, As, Bs, wid, lrow, lcolsw);
      asm volatile("s_waitcnt vmcnt(6)" ::: "memory");
    } else if (t + 1 < NKT) {
      asm volatile("s_waitcnt vmcnt(0)" ::: "memory");
    }
    __builtin_amdgcn_s_barrier();
  }
}

// -------- K4: qkv GEMM (256x128, n-major) + fused RMS+SCALE --------
__global__ __launch_bounds__(512) void gemm_qkv(
    const short* __restrict__ A, const short* __restrict__ Wt, const float* __restrict__ bias,
    __hip_bfloat16* __restrict__ q, __hip_bfloat16* __restrict__ k, __hip_bfloat16* __restrict__ v) {
  __shared__ short Al[256 * 64], Bl[128 * 64];
  f32x4 acc[4][4];
  int wgid = swz_wgid(blockIdx.x, 37 * 18);
  int m0 = (wgid % 37) * 256, n0 = (wgid / 37) * 128;
  mfma_core_256(A, Wt, DIM, m0, n0, acc, Al, Bl);
  int tid = threadIdx.x, lane = tid & 63, wid = tid >> 6, wr = wid >> 1, wc = wid & 1;
  int ln15 = lane & 15, lq = lane >> 4;
  int colbase = n0 + wc * 64;
  int which = colbase / DIM;
  int rem = colbase - which * DIM;
  int h = rem >> 6;
  __hip_bfloat16* dst = (which == 0) ? q : ((which == 1) ? k : v);
  float fin_scale = (which == 0) ? SCALE : 1.0f;
  float bv[4];
  #pragma unroll
  for (int j = 0; j < 4; j++) bv[j] = bias[colbase + j * 16 + ln15];
  #pragma unroll
  for (int i = 0; i < 4; i++) {
    #pragma unroll
    for (int r = 0; r < 4; r++) {
      int m = m0 + wr * 64 + i * 16 + lq * 4 + r;
      float v4[4];
      #pragma unroll
      for (int j = 0; j < 4; j++) v4[j] = acc[i][j][r] + bv[j];
      float inv = fin_scale;
      if (which < 2) {
        float ss = v4[0]*v4[0] + v4[1]*v4[1] + v4[2]*v4[2] + v4[3]*v4[3];
        ss += __shfl_xor(ss, 1); ss += __shfl_xor(ss, 2);
        ss += __shfl_xor(ss, 4); ss += __shfl_xor(ss, 8);
        inv = rsqrtf(ss * (1.f / 64.f) + 1e-6f) * fin_scale;
      }
      if (m < BATCH * NTOK) {
        int b = m / NTOK, n = m - b * NTOK;
        __hip_bfloat16* orow = dst + (((size_t)b * NH + h) * NTOK + n) * HDIM;
        #pragma unroll
        for (int j = 0; j < 4; j++)
          orow[j * 16 + ln15] = __float2bfloat16(v4[j] * inv);
      }
    }
  }
}

// -------- K6: MFMA flash attention, 128 q-rows, dbuf K/V, T14 reg-split staging --------
__global__ __launch_bounds__(512) void attn_mfma(
    const short* __restrict__ q, const short* __restrict__ k,
    const short* __restrict__ vT, const float* __restrict__ s,
    const float* __restrict__ g, const float* __restrict__ alpha,
    const float* __restrict__ sbs, short* __restrict__ ao) {
  __shared__ short Kh[2][64 * KHS];
  __shared__ short Vt[2][64 * VTS];
  __shared__ short Pl[8][16 * PLS];
  int xcd = blockIdx.x & 7, idx = blockIdx.x >> 3;
  int bh = xcd * 24 + idx / 5;
  int n0 = (idx % 5) * 128;
  int b = bh / NH, h = bh - b * NH;
  int tid = threadIdx.x, lane = tid & 63, w = tid >> 6;
  int l15 = lane & 15, lg = lane >> 4;
  float a = alpha[0], c = a * sbs[0];
  const short* qb = q + (size_t)bh * NTOK * HDIM;
  const short* kb = k + (size_t)bh * NTOK * HDIM;
  const short* vtb = vT + (size_t)bh * HDIM * NTOKP;
  const float* sb = s + (size_t)b * NTOK * SDIM;
  const bf16x8 Z8 = {0, 0, 0, 0, 0, 0, 0, 0};

  int qrow = n0 + w * 16 + l15;
  int qsrc = (qrow < NTOK) ? qrow : 0;
  bf16x8 qf0 = *(const bf16x8*)(qb + (size_t)qsrc * HDIM + lg * 8);
  bf16x8 qf1 = *(const bf16x8*)(qb + (size_t)qsrc * HDIM + 32 + lg * 8);
  bf16x8 qf2 = Z8;
  if (lg < 2) {
    const float* sp = sb + (size_t)qsrc * SDIM + lg * 8;
    #pragma unroll
    for (int j = 0; j < 8; j++) qf2[j] = f2b(c * sp[j]);
  }

  f32x4 accO[4];
  #pragma unroll
  for (int dd = 0; dd < 4; dd++) accO[dd] = (f32x4){0.f, 0.f, 0.f, 0.f};
  float rsum[4] = {0.f, 0.f, 0.f, 0.f};

  int srow = (tid & 255) >> 2, sseg = tid & 3;
  if (tid < 256 && sseg == 3) {
    #pragma unroll
    for (int bb = 0; bb < 2; bb++) {
      short* dst = Kh[bb] + srow * KHS + 80;
      *(bf16x8*)dst = Z8;
      *(bf16x8*)(dst + 8) = Z8;
    }
  }

  // ---- prologue: stage tile 0 ----
  if (tid < 256) {
    int key = srow;
    bool kok = key < NTOK;
    if (sseg < 2) {
      bf16x8 v0 = Z8, v1 = Z8, v2 = Z8, v3 = Z8;
      if (kok) {
        const short* src = kb + (size_t)key * HDIM + sseg * 32;
        v0 = *(const bf16x8*)(src);
        v1 = *(const bf16x8*)(src + 8);
        v2 = *(const bf16x8*)(src + 16);
        v3 = *(const bf16x8*)(src + 24);
      }
      short* dst = Kh[0] + srow * KHS + sseg * 32;
      *(bf16x8*)dst = v0;
      *(bf16x8*)(dst + 8) = v1;
      *(bf16x8*)(dst + 16) = v2;
      *(bf16x8*)(dst + 24) = v3;
    } else if (sseg == 2) {
      bf16x8 v0 = Z8, v1 = Z8;
      if (kok) {
        const float* sp = sb + (size_t)key * SDIM;
        #pragma unroll
        for (int j = 0; j < 8; j++) { v0[j] = f2b(sp[j]); v1[j] = f2b(sp[j + 8]); }
      }
      short* dst = Kh[0] + srow * KHS + 64;
      *(bf16x8*)dst = v0;
      *(bf16x8*)(dst + 8) = v1;
    }
  } else {
    int kk0 = sseg * 16;
    const short* src = vtb + (size_t)srow * NTOKP + kk0;
    short* dst = Vt[0] + srow * VTS + kk0;
    *(bf16x8*)dst = *(const bf16x8*)src;
    *(bf16x8*)(dst + 8) = *(const bf16x8*)(src + 8);
  }
  __syncthreads();

  const int NT = 10;
  for (int ti = 0; ti < NT; ti++) {
    int mt = ti * 64, cur = ti & 1;
    const short* KhC = Kh[cur];
    const short* VtC = Vt[cur];
    bool nxt = (ti + 1 < NT);
    int mtn = mt + 64;
    // ---- T14 stage-load: next tile's globals into registers ----
    bf16x8 kr0 = Z8, kr1 = Z8, kr2 = Z8, kr3 = Z8;
    float4 sf0 = {0,0,0,0}, sf1 = {0,0,0,0}, sf2 = {0,0,0,0}, sf3 = {0,0,0,0};
    if (nxt) {
      if (tid < 256) {
        int key = mtn + srow;
        bool kok = key < NTOK;
        if (sseg < 2) {
          if (kok) {
            const short* src = kb + (size_t)key * HDIM + sseg * 32;
            kr0 = *(const bf16x8*)(src);
            kr1 = *(const bf16x8*)(src + 8);
            kr2 = *(const bf16x8*)(src + 16);
            kr3 = *(const bf16x8*)(src + 24);
          }
        } else if (sseg == 2) {
          if (kok) {
            const float* sp = sb + (size_t)key * SDIM;
            sf0 = *(const float4*)(sp);
            sf1 = *(const float4*)(sp + 4);
            sf2 = *(const float4*)(sp + 8);
            sf3 = *(const float4*)(sp + 12);
          }
        }
      } else {
        int kk0 = sseg * 16;
        const short* src = vtb + (size_t)srow * NTOKP + mtn + kk0;
        kr0 = *(const bf16x8*)src;
        kr1 = *(const bf16x8*)(src + 8);
      }
    }
    // ---- QK from Kh[cur] ----
    f32x4 sa[4];
    __builtin_amdgcn_s_setprio(1);
    #pragma unroll
    for (int jj = 0; jj < 4; jj++) {
      sa[jj] = (f32x4){0.f, 0.f, 0.f, 0.f};
      const short* kp = KhC + (jj * 16 + l15) * KHS + lg * 8;
      sa[jj] = __builtin_amdgcn_mfma_f32_16x16x32_bf16(qf0, *(const bf16x8*)kp, sa[jj], 0, 0, 0);
      sa[jj] = __builtin_amdgcn_mfma_f32_16x16x32_bf16(qf1, *(const bf16x8*)(kp + 32), sa[jj], 0, 0, 0);
      sa[jj] = __builtin_amdgcn_mfma_f32_16x16x32_bf16(qf2, *(const bf16x8*)(kp + 64), sa[jj], 0, 0, 0);
    }
    __builtin_amdgcn_s_setprio(0);
    // ---- T14 stage-write: regs -> buf[cur^1] ----
    if (nxt) {
      if (tid < 256) {
        if (sseg < 2) {
          short* dst = Kh[cur ^ 1] + srow * KHS + sseg * 32;
          *(bf16x8*)dst = kr0;
          *(bf16x8*)(dst + 8) = kr1;
          *(bf16x8*)(dst + 16) = kr2;
          *(bf16x8*)(dst + 24) = kr3;
        } else if (sseg == 2) {
          bf16x8 v0, v1;
          v0[0] = f2b(sf0.x); v0[1] = f2b(sf0.y); v0[2] = f2b(sf0.z); v0[3] = f2b(sf0.w);
          v0[4] = f2b(sf1.x); v0[5] = f2b(sf1.y); v0[6] = f2b(sf1.z); v0[7] = f2b(sf1.w);
          v1[0] = f2b(sf2.x); v1[1] = f2b(sf2.y); v1[2] = f2b(sf2.z); v1[3] = f2b(sf2.w);
          v1[4] = f2b(sf3.x); v1[5] = f2b(sf3.y); v1[6] = f2b(sf3.z); v1[7] = f2b(sf3.w);
          short* dst = Kh[cur ^ 1] + srow * KHS + 64;
          *(bf16x8*)dst = v0;
          *(bf16x8*)(dst + 8) = v1;
        }
      } else {
        int kk0 = sseg * 16;
        short* dst = Vt[cur ^ 1] + srow * VTS + kk0;
        *(bf16x8*)dst = kr0;
        *(bf16x8*)(dst + 8) = kr1;
      }
    }
    // ---- softmax -> Pl ----
    short* pw = Pl[w];
    float ps[4][4];
    #pragma unroll
    for (int jj = 0; jj < 4; jj++) {
      bool ok = (mt + jj * 16 + l15) < NTOK;
      #pragma unroll
      for (int r = 0; r < 4; r++) {
        float x = sa[jj][r];
        x = fminf(fmaxf(x, -CLIPV), CLIPV);
        float e = ok ? __expf(x) : 0.f;
        ps[jj][r] = e;
        pw[(lg * 4 + r) * PLS + jj * 16 + l15] = f2b(e);
      }
    }
    #pragma unroll
    for (int r = 0; r < 4; r++) {
      float t = ps[0][r] + ps[1][r] + ps[2][r] + ps[3][r];
      t += __shfl_xor(t, 1); t += __shfl_xor(t, 2);
      t += __shfl_xor(t, 4); t += __shfl_xor(t, 8);
      rsum[r] += t;
    }
    // ---- PV from Vt[cur] ----
    __builtin_amdgcn_s_setprio(1);
    #pragma unroll
    for (int kc = 0; kc < 2; kc++) {
      bf16x8 pa = *(const bf16x8*)(pw + l15 * PLS + kc * 32 + lg * 8);
      #pragma unroll
      for (int dd = 0; dd < 4; dd++) {
        bf16x8 vf = *(const bf16x8*)(VtC + (dd * 16 + l15) * VTS + kc * 32 + lg * 8);
        accO[dd] = __builtin_amdgcn_mfma_f32_16x16x32_bf16(pa, vf, accO[dd], 0, 0, 0);
      }
    }
    __builtin_amdgcn_s_setprio(0);
    __syncthreads();
  }
  float gm = 1.f + a * g[bh];
  #pragma unroll
  for (int r = 0; r < 4; r++) {
    int n = n0 + w * 16 + lg * 4 + r;
    if (n >= NTOK) continue;
    float inv = gm / rsum[r];
    short* orow = ao + ((size_t)b * NTOK + n) * DIM + h * HDIM;
    #pragma unroll
    for (int dd = 0; dd < 4; dd++)
      orow[dd * 16 + l15] = f2b(accO[dd][r] * inv);
  }
}

// -------- K7: proj GEMM (64x128 counted, n-major) + residual --------
__global__ __launch_bounds__(256) void gemm_proj(
    const short* __restrict__ A, const short* __restrict__ Wt, const float* __restrict__ bias,
    float* __restrict__ xw, float* __restrict__ out) {
  __shared__ short Al0[64 * 64], Bl0[128 * 64], Al1[64 * 64], Bl1[128 * 64];
  f32x4 acc[4][2];
  int wgid = swz_wgid(blockIdx.x, 145 * 6);
  int m0 = (wgid % 145) * 64, n0 = (wgid / 145) * 128;
  mfma_core_64(A, Wt, DIM, m0, n0, acc, Al0, Bl0, Al1, Bl1);
  int tid = threadIdx.x, lane = tid & 63, wid = tid >> 6;
  int ln15 = lane & 15, lq = lane >> 4;
  #pragma unroll
  for (int i = 0; i < 4; i++) {
    #pragma unroll
    for (int j = 0; j < 2; j++) {
      int col = n0 + wid * 32 + j * 16 + ln15;
      float bv = bias[col];
      #pragma unroll
      for (int r = 0; r < 4; r++) {
        int m = m0 + i * 16 + lq * 4 + r;
        if (m >= BATCH * NTOK) continue;
        int n = m % NTOK;
        float val = acc[i][j][r] + bv + xw[(size_t)m * DIM + col];
        xw[(size_t)m * DIM + col] = val;
        if (n < 2) out[(size_t)m * DIM + col] = val;
      }
    }
  }
}

// -------- K8: LN for MLP -> xm bf16 --------
__global__ __launch_bounds__(256) void ln_mlp_kernel(
    const float* __restrict__ x2, const float* __restrict__ w, const float* __restrict__ bb,
    __hip_bfloat16* __restrict__ xm) {
  int r = blockIdx.x;
  int b = r / NP, pi = r % NP;
  int tid = threadIdx.x;
  const float* xr = x2 + ((size_t)b * NTOK + 2 + pi) * DIM;
  float vals[3];
  #pragma unroll
  for (int j = 0; j < 3; j++) vals[j] = xr[tid + j * 256];
  float s = vals[0] + vals[1] + vals[2];
  float ss = vals[0]*vals[0] + vals[1]*vals[1] + vals[2]*vals[2];
  block_reduce2(s, ss);
  float mean = s * (1.f / 768.f);
  float inv = rsqrtf(ss * (1.f / 768.f) - mean * mean + 1e-6f);
  __hip_bfloat16* xo = xm + (size_t)r * DIM;
  #pragma unroll
  for (int j = 0; j < 3; j++) {
    int d = tid + j * 256;
    xo[d] = __float2bfloat16((vals[j] - mean) * inv * w[d] + bb[d]);
  }
}

// -------- K9: fc1 GEMM (256x128 n-major, chunk) + GELU --------
__global__ __launch_bounds__(512) void gemm_fc1(
    const short* __restrict__ A, const short* __restrict__ Wt, const float* __restrict__ bias,
    __hip_bfloat16* __restrict__ h1) {
  __shared__ short Al[256 * 64], Bl[128 * 64];
  f32x4 acc[4][4];
  int wgid = swz_wgid(blockIdx.x, 18 * 24);
  int m0 = (wgid % 18) * 256, n0 = (wgid / 18) * 128;
  mfma_core_256(A, Wt, DIM, m0, n0, acc, Al, Bl);
  int tid = threadIdx.x, lane = tid & 63, wid = tid >> 6, wr = wid >> 1, wc = wid & 1;
  int ln15 = lane & 15, lq = lane >> 4;
  #pragma unroll
  for (int i = 0; i < 4; i++) {
    #pragma unroll
    for (int j = 0; j < 4; j++) {
      int col = n0 + wc * 64 + j * 16 + ln15;
      float bv = bias[col];
      #pragma unroll
      for (int r = 0; r < 4; r++) {
        int m = m0 + wr * 64 + i * 16 + lq * 4 + r;
        float val = acc[i][j][r] + bv;
        float ge = 0.5f * val * (1.f + erff(val * 0.70710678118f));
        h1[(size_t)m * HID + col] = __float2bfloat16(ge);
      }
    }
  }
}

// -------- K10: depthwise 3x3 conv + SiLU --------
__global__ __launch_bounds__(256) void dwconv_kernel(
    const __hip_bfloat16* __restrict__ h1, const float* __restrict__ dwt,
    const float* __restrict__ dwb, __hip_bfloat16* __restrict__ h2) {
  int gx = blockIdx.x;
  int b = gx / 144, g = gx - b * 144;
  int y = g / 6, x0 = (g - y * 6) * 4;
  int tid = threadIdx.x;
  int c0 = blockIdx.y * 512 + (tid & 63) * 8;
  int x = x0 + (tid >> 6);
  const short* in = (const short*)h1 + (size_t)b * NP * HID + c0;
  bf16x8 iv[3][3];
  #pragma unroll
  for (int ky = 0; ky < 3; ky++) {
    int yy = y + ky - 1;
    #pragma unroll
    for (int kx = 0; kx < 3; kx++) {
      int xx = x + kx - 1;
      bool ok = (yy >= 0 && yy < PGRID && xx >= 0 && xx < PGRID);
      iv[ky][kx] = ok ? *(const bf16x8*)(in + (size_t)(yy * PGRID + xx) * HID)
                      : (bf16x8){0, 0, 0, 0, 0, 0, 0, 0};
    }
  }
  float acc[8];
  {
    float4 b0 = *(const float4*)(dwb + c0);
    float4 b1 = *(const float4*)(dwb + c0 + 4);
    acc[0] = b0.x; acc[1] = b0.y; acc[2] = b0.z; acc[3] = b0.w;
    acc[4] = b1.x; acc[5] = b1.y; acc[6] = b1.z; acc[7] = b1.w;
  }
  #pragma unroll
  for (int t = 0; t < 9; t++) {
    float4 w0 = *(const float4*)(dwt + t * HID + c0);
    float4 w1 = *(const float4*)(dwt + t * HID + c0 + 4);
    bf16x8 xv = iv[t / 3][t % 3];
    acc[0] += b2f(xv[0]) * w0.x; acc[1] += b2f(xv[1]) * w0.y;
    acc[2] += b2f(xv[2]) * w0.z; acc[3] += b2f(xv[3]) * w0.w;
    acc[4] += b2f(xv[4]) * w1.x; acc[5] += b2f(xv[5]) * w1.y;
    acc[6] += b2f(xv[6]) * w1.z; acc[7] += b2f(xv[7]) * w1.w;
  }
  short ov[8];
  #pragma unroll
  for (int e = 0; e < 8; e++) {
    float v = acc[e];
    ov[e] = f2b(v / (1.f + __expf(-v)));
  }
  *(bf16x8*)((short*)h2 + ((size_t)b * NP + y * PGRID + x) * HID + c0) = *(bf16x8*)ov;
}

// -------- K11: fc2 GEMM (64x128 counted, n-major, chunk) + residual --------
__global__ __launch_bounds__(256) void gemm_fc2(
    const short* __restrict__ A, const short* __restrict__ Wt, const float* __restrict__ bias,
    const float* __restrict__ xw, float* __restrict__ out, int b0) {
  __shared__ short Al0[64 * 64], Bl0[128 * 64], Al1[64 * 64], Bl1[128 * 64];
  f32x4 acc[4][2];
  int wgid = swz_wgid(blockIdx.x, 72 * 6);
  int m0 = (wgid % 72) * 64, n0 = (wgid / 72) * 128;
  mfma_core_64(A, Wt, HID, m0, n0, acc, Al0, Bl0, Al1, Bl1);
  int tid = threadIdx.x, lane = tid & 63, wid = tid >> 6;
  int ln15 = lane & 15, lq = lane >> 4;
  #pragma unroll
  for (int i = 0; i < 4; i++) {
    #pragma unroll
    for (int j = 0; j < 2; j++) {
      int col = n0 + wid * 32 + j * 16 + ln15;
      float bv = bias[col];
      #pragma unroll
      for (int r = 0; r < 4; r++) {
        int m = m0 + i * 16 + lq * 4 + r;
        int bl = m / NP, pi = m - bl * NP;
        size_t orow = ((size_t)(b0 + bl) * NTOK + 2 + pi) * DIM;
        out[orow + col] = acc[i][j][r] + bv + xw[orow + col];
      }
    }
  }
}

extern "C" void kernel_launch(void* const* d_in, const int* in_sizes, int n_in,
                              void* d_out, int out_size, void* d_ws, size_t ws_size,
                              hipStream_t stream) {
  const float* x      = (const float*)d_in[0];
  const float* ftc    = (const float*)d_in[2];
  const float* fsum   = (const float*)d_in[3];
  const float* tbf    = (const float*)d_in[4];
  const float* alpha  = (const float*)d_in[5];
  const float* lgw    = (const float*)d_in[6];
  const float* lgb    = (const float*)d_in[7];
  const float* film_w = (const float*)d_in[8];
  const float* film_b = (const float*)d_in[9];
  const float* law    = (const float*)d_in[10];
  const float* lab    = (const float*)d_in[11];
  const float* qkv_w  = (const float*)d_in[12];
  const float* qkv_b  = (const float*)d_in[13];
  const float* proj_w = (const float*)d_in[14];
  const float* proj_b = (const float*)d_in[15];
  const float* sbs    = (const float*)d_in[16];
  const float* gate_w = (const float*)d_in[17];
  const float* gate_b = (const float*)d_in[18];
  const float* band_w = (const float*)d_in[19];
  const float* lmw    = (const float*)d_in[20];
  const float* lmb    = (const float*)d_in[21];
  const float* fc1_w  = (const float*)d_in[22];
  const float* fc1_b  = (const float*)d_in[23];
  const float* fc2_w  = (const float*)d_in[24];
  const float* fc2_b  = (const float*)d_in[25];
  const float* dw_w   = (const float*)d_in[26];
  const float* dw_b   = (const float*)d_in[27];
  float* out = (float*)d_out;

  float* ws = (float*)d_ws;
  const size_t SZ = (size_t)BATCH * NTOK * DIM;  // 7,102,464

  float* p_xw = ws;
  short* p_xn = (short*)(ws + SZ);
  short* p_q  = (short*)(ws + SZ + SZ / 2);
  short* p_k  = (short*)(ws + 2 * SZ);
  short* p_v  = (short*)(ws + 2 * SZ + SZ / 2);
  float* p_s  = ws + 3 * SZ;
  float* p_gamma = p_s + (size_t)BATCH * NTOK * SDIM;
  float* p_beta  = p_gamma + BATCH * DIM;
  float* p_g     = p_beta + BATCH * DIM;
  float* p_dwt   = p_g + 256;
  float* p_part  = p_dwt + 9 * HID;
  float* wtb = p_part + (size_t)FKS * BATCH * 1536;
  short* qkvT = (short*)wtb;
  short* projT = qkvT + (size_t)768 * 2304;
  short* fc1T  = projT + (size_t)768 * 768;
  short* fc2T  = fc1T + (size_t)768 * 3072;
  short* h2c   = fc2T + (size_t)3072 * 768;

  const size_t total_floats =
      3 * SZ + (size_t)BATCH * NTOK * SDIM + 2 * (size_t)BATCH * DIM + 256 + 9 * HID +
      (size_t)FKS * BATCH * 1536 +
      ((size_t)768 * 2304 + 768 * 768 + 768 * 3072 + 3072 * 768) / 2 +
      ((size_t)8 * NP * HID) / 2;
  if (ws_size < total_floats * sizeof(float)) return;

  short* p_ao = p_xn;
  short* p_xm = p_q;
  short* h1c  = p_k;
  short* p_vT = h2c;

  dim3 blk(256);

  // fused prologue: weight transposes + dwt + film_part + band_s (independent)
  prologue_kernel<<<dim3(1310), blk, 0, stream>>>(
      qkv_w, proj_w, fc1_w, fc2_w, dw_w, fsum, film_w, tbf, band_w,
      qkvT, projT, fc1T, fc2T, p_dwt, p_part, p_s);

  film_fin<<<dim3(96 + 48), blk, 0, stream>>>(
      p_part, film_b, ftc, gate_w, gate_b, p_gamma, p_beta, p_g);

  ln_film_kernel<<<dim3(BATCH * NTOK), blk, 0, stream>>>(
      x, p_gamma, p_beta, lgw, lgb, law, lab, alpha, p_xw, (__hip_bfloat16*)p_xn);

  gemm_qkv<<<dim3(37 * 18), dim3(512), 0, stream>>>(
      p_xn, qkvT, qkv_b, (__hip_bfloat16*)p_q, (__hip_bfloat16*)p_k, (__hip_bfloat16*)p_v);

  transpose_v<<<dim3(10, BATCH * NH), blk, 0, stream>>>(p_v, p_vT);

  attn_mfma<<<dim3(960), dim3(512), 0, stream>>>(
      p_q, p_k, p_vT, p_s, p_g, alpha, sbs, p_ao);

  gemm_proj<<<dim3(145 * 6), blk, 0, stream>>>(p_ao, projT, proj_b, p_xw, out);

  ln_mlp_kernel<<<dim3(BATCH * NP), blk, 0, stream>>>(p_xw, lmw, lmb, (__hip_bfloat16*)p_xm);

  for (int cc = 0; cc < 2; cc++) {
    const short* Ach = p_xm + (size_t)cc * 4608 * DIM;
    gemm_fc1<<<dim3(18 * 24), dim3(512), 0, stream>>>(Ach, fc1T, fc1_b, (__hip_bfloat16*)h1c);
    dwconv_kernel<<<dim3(8 * 144, 6), blk, 0, stream>>>(
        (const __hip_bfloat16*)h1c, p_dwt, dw_b, (__hip_bfloat16*)h2c);
    gemm_fc2<<<dim3(72 * 6), blk, 0, stream>>>(h2c, fc2T, fc2_b, p_xw, out, cc * 8);
  }
}